// Round 8
// baseline (1228.127 us; speedup 1.0000x reference)
//
#include <hip/hip_runtime.h>
#include <hip/hip_bf16.h>
#include <math.h>

#define N_NODES 25000
#define N_EDGES 400000
#define NFEAT   256
#define NHID    32
#define NHEAD   12
#define HC      384
#define NEG_SLOPE 0.2f

__device__ __forceinline__ float bf2f(unsigned short u) {
    union { unsigned int i; float f; } v; v.i = ((unsigned int)u) << 16; return v.f;
}
__device__ __forceinline__ unsigned short f2bf(float f) {
    union { float f; unsigned int i; } v; v.f = f;
    unsigned int x = v.i;
    unsigned int r = (x + 0x7FFFu + ((x >> 16) & 1u)) >> 16;
    return (unsigned short)r;
}
__device__ __forceinline__ int clampN(int s) {
    return ((unsigned)s < (unsigned)N_NODES) ? s : 0;
}
__device__ __forceinline__ float ldf(const void* p, size_t i, int isF32) {
    return isF32 ? ((const float*)p)[i] : bf2f(((const unsigned short*)p)[i]);
}
__device__ __forceinline__ int ldi(const void* p, size_t i, int isI64) {
    return isI64 ? (int)((const unsigned int*)p)[2 * i] : ((const int*)p)[i];
}

// ---------------- dtype detection (1 block) ----------------
__global__ void detect_kernel(const unsigned short* __restrict__ xr,
                              const unsigned int* __restrict__ eir,
                              int* __restrict__ flags) {
    __shared__ int sF, sI;
    if (threadIdx.x == 0) { sF = 0; sI = 0; }
    __syncthreads();
    int t = threadIdx.x;
    int cf = 0, ci = 0;
#pragma unroll
    for (int i = 0; i < 4; i++) {
        unsigned short u = xr[2 * (t * 4 + i)];
        int e = (u >> 7) & 0xFF;
        if (e >= 100 && e <= 140) cf++;
        unsigned int v = eir[2 * (t * 4 + i) + 1];
        if (v == 0u) ci++;
    }
    atomicAdd(&sF, cf);
    atomicAdd(&sI, ci);
    __syncthreads();
    if (threadIdx.x == 0) {
        flags[0] = (sF >= 614) ? 0 : 1;   // 1 -> float inputs are f32
        flags[1] = (sI >= 512) ? 1 : 0;   // 1 -> edge_index is i64
    }
}

// ---------------- prep: fold W_e1*att_e -> M1[32x12] ----------------
__global__ void prep_kernel(const void* __restrict__ We1,
                            const void* __restrict__ att_e,
                            const int* __restrict__ flags,
                            float* __restrict__ M1) {
    int isF32 = flags[0];
    int id = blockIdx.x * 256 + threadIdx.x;
    if (id < 32 * 12) {
        int k = id / 12, h = id % 12;
        float s = 0.f;
        for (int c = 0; c < 32; c++)
            s += ldf(We1, (size_t)k * HC + h * 32 + c, isF32) *
                 ldf(att_e, (size_t)h * 32 + c, isF32);
        M1[k * 12 + h] = s;
    }
}

// ---------------- CSR build ----------------
__global__ void hist_kernel(const void* __restrict__ ei, const int* __restrict__ flags,
                            int* __restrict__ cnt) {
    int isI64 = flags[1];
    int e = blockIdx.x * 256 + threadIdx.x;
    if (e < N_EDGES) {
        int d = clampN(ldi(ei, (size_t)N_EDGES + e, isI64));
        atomicAdd(&cnt[d], 1);
    }
}

__global__ void scan_kernel(const int* __restrict__ cnt, int* __restrict__ rowptr,
                            int* __restrict__ wofs) {
    __shared__ int buf[256];
    __shared__ int carry_s;
    int tid = threadIdx.x;
    if (tid == 0) { rowptr[0] = 0; carry_s = 0; }
    __syncthreads();
    for (int base = 0; base < N_NODES; base += 256) {
        int i = base + tid;
        int v = (i < N_NODES) ? cnt[i] : 0;
        buf[tid] = v;
        __syncthreads();
        for (int offd = 1; offd < 256; offd <<= 1) {
            int t = (tid >= offd) ? buf[tid - offd] : 0;
            __syncthreads();
            buf[tid] += t;
            __syncthreads();
        }
        int incl = buf[tid];
        int carry = carry_s;
        if (i < N_NODES) { rowptr[i + 1] = carry + incl; wofs[i] = carry + incl - v; }
        __syncthreads();
        if (tid == 255) carry_s += buf[255];
        __syncthreads();
    }
}

__global__ void scatter_kernel(const void* __restrict__ ei,
                               const void* __restrict__ ea, const int* __restrict__ flags,
                               const float* __restrict__ M1,
                               int* __restrict__ wofs, int* __restrict__ src_sorted,
                               unsigned short* __restrict__ alpha_e) {
    __shared__ float sM[32 * 12];
    for (int i = threadIdx.x; i < 384; i += 256) sM[i] = M1[i];
    __syncthreads();
    int isF32 = flags[0], isI64 = flags[1];
    int e = blockIdx.x * 256 + threadIdx.x;
    if (e >= N_EDGES) return;
    int d = clampN(ldi(ei, (size_t)N_EDGES + e, isI64));
    int pos = atomicAdd(&wofs[d], 1);
    if ((unsigned)pos >= (unsigned)N_EDGES) return;
    src_sorted[pos] = clampN(ldi(ei, (size_t)e, isI64));
    float ev[12];
#pragma unroll
    for (int h = 0; h < 12; h++) ev[h] = 0.f;
#pragma unroll
    for (int k = 0; k < 32; k++) {
        float a = ldf(ea, (size_t)e * 32 + k, isF32);
#pragma unroll
        for (int h = 0; h < 12; h++) ev[h] += a * sM[k * 12 + h];
    }
#pragma unroll
    for (int h = 0; h < 12; h++) alpha_e[(size_t)pos * 12 + h] = f2bf(ev[h]);
}

// ---------------- VALU GEMM: C[M x 384](bf16) = A[M x K] * W[K x 384] ----------------
__global__ __launch_bounds__(256) void gemm_valu(const void* __restrict__ A,
                                                 const void* __restrict__ W,
                                                 const int* __restrict__ flags,
                                                 int aFromFlag,
                                                 unsigned short* __restrict__ C,
                                                 int M, int K) {
    __shared__ float sA[64][33];
    __shared__ float sW[32][64];
    int isF32 = flags[0];
    int aF32 = aFromFlag ? isF32 : 0;
    int tid = threadIdx.x;
    int m0 = blockIdx.x * 64, n0 = blockIdx.y * 64;
    int tx = tid & 15, ty = tid >> 4;
    float acc[4][4];
#pragma unroll
    for (int i = 0; i < 4; i++)
#pragma unroll
        for (int j = 0; j < 4; j++) acc[i][j] = 0.f;
    for (int k0 = 0; k0 < K; k0 += 32) {
        for (int i = tid; i < 64 * 32; i += 256) {
            int r = i >> 5, c = i & 31;
            int row = m0 + r; if (row >= M) row = M - 1;
            sA[r][c] = ldf(A, (size_t)row * K + k0 + c, aF32);
        }
        for (int i = tid; i < 32 * 64; i += 256) {
            int r = i >> 6, c = i & 63;
            sW[r][c] = ldf(W, (size_t)(k0 + r) * HC + n0 + c, isF32);
        }
        __syncthreads();
#pragma unroll 8
        for (int kk = 0; kk < 32; kk++) {
            float a[4], w[4];
#pragma unroll
            for (int i = 0; i < 4; i++) a[i] = sA[ty + 16 * i][kk];
#pragma unroll
            for (int j = 0; j < 4; j++) w[j] = sW[kk][tx + 16 * j];
#pragma unroll
            for (int i = 0; i < 4; i++)
#pragma unroll
                for (int j = 0; j < 4; j++) acc[i][j] += a[i] * w[j];
        }
        __syncthreads();
    }
#pragma unroll
    for (int i = 0; i < 4; i++) {
        int row = m0 + ty + 16 * i;
        if (row < M) {
#pragma unroll
            for (int j = 0; j < 4; j++)
                C[(size_t)row * HC + n0 + tx + 16 * j] = f2bf(acc[i][j]);
        }
    }
}

// ---------------- per-(node,head) attention logits ----------------
__global__ void att_kernel(const unsigned short* __restrict__ hx,
                           const void* __restrict__ att_src,
                           const void* __restrict__ att_dst,
                           const int* __restrict__ flags,
                           float* __restrict__ a_s, float* __restrict__ a_d) {
    int isF32 = flags[0];
    int id = blockIdx.x * 256 + threadIdx.x;
    if (id >= N_NODES * NHEAD) return;
    int n = id / 12, h = id % 12;
    const unsigned short* row = hx + (size_t)n * HC + h * 32;
    float s = 0.f, d = 0.f;
#pragma unroll
    for (int c = 0; c < 32; c++) {
        float v = bf2f(row[c]);
        s += v * ldf(att_src, (size_t)h * 32 + c, isF32);
        d += v * ldf(att_dst, (size_t)h * 32 + c, isF32);
    }
    a_s[id] = s;
    a_d[id] = d;
}

// ---------------- segment softmax per destination node ----------------
__global__ __launch_bounds__(256) void softmax_kernel(const float* __restrict__ a_s,
                                                      const float* __restrict__ a_d,
                                                      const int* __restrict__ rowptr,
                                                      const int* __restrict__ src_sorted,
                                                      unsigned short* __restrict__ alpha_e,
                                                      float* __restrict__ alpha_loop,
                                                      int has_ae) {
    int lane = threadIdx.x & 63;
    int node = blockIdx.x * 4 + (threadIdx.x >> 6);
    if (node >= N_NODES) return;
    int start = rowptr[node], end = rowptr[node + 1];
    if (start < 0) start = 0;
    if (end > N_EDGES) end = N_EDGES;
    int deg = end - start;
    float adn[12], asn[12], mx[12], sae[12];
#pragma unroll
    for (int h = 0; h < 12; h++) {
        adn[h] = a_d[node * 12 + h];
        asn[h] = a_s[node * 12 + h];
        mx[h] = -1e30f;
        sae[h] = 0.f;
    }
    for (int p = start + lane; p < end; p += 64) {
        int s = clampN(src_sorted[p]);
#pragma unroll
        for (int h = 0; h < 12; h++) {
            float ev = a_s[s * 12 + h] + adn[h];
            if (has_ae) { float a = bf2f(alpha_e[(size_t)p * 12 + h]); sae[h] += a; ev += a; }
            ev = ev > 0.f ? ev : NEG_SLOPE * ev;
            alpha_e[(size_t)p * 12 + h] = f2bf(ev);
            mx[h] = fmaxf(mx[h], ev);
        }
    }
#pragma unroll
    for (int off = 1; off < 64; off <<= 1) {
#pragma unroll
        for (int h = 0; h < 12; h++) {
            mx[h] = fmaxf(mx[h], __shfl_xor(mx[h], off));
            if (has_ae) sae[h] += __shfl_xor(sae[h], off);
        }
    }
    float el[12], den[12];
    float invdeg = 1.f / fmaxf((float)deg, 1.f);
#pragma unroll
    for (int h = 0; h < 12; h++) {
        float v = asn[h] + adn[h] + (has_ae ? sae[h] * invdeg : 0.f);
        v = v > 0.f ? v : NEG_SLOPE * v;
        el[h] = v;
        mx[h] = fmaxf(mx[h], v);
        den[h] = 0.f;
    }
    for (int p = start + lane; p < end; p += 64) {
#pragma unroll
        for (int h = 0; h < 12; h++) {
            float ex = expf(bf2f(alpha_e[(size_t)p * 12 + h]) - mx[h]);
            alpha_e[(size_t)p * 12 + h] = f2bf(ex);
            den[h] += ex;
        }
    }
#pragma unroll
    for (int off = 1; off < 64; off <<= 1) {
#pragma unroll
        for (int h = 0; h < 12; h++) den[h] += __shfl_xor(den[h], off);
    }
    float exl[12], rden[12];
#pragma unroll
    for (int h = 0; h < 12; h++) {
        exl[h] = expf(el[h] - mx[h]);
        den[h] += exl[h];
        rden[h] = 1.f / den[h];
    }
    for (int p = start + lane; p < end; p += 64) {
#pragma unroll
        for (int h = 0; h < 12; h++)
            alpha_e[(size_t)p * 12 + h] = f2bf(bf2f(alpha_e[(size_t)p * 12 + h]) * rden[h]);
    }
    if (lane == 0) {
#pragma unroll
        for (int h = 0; h < 12; h++)
            alpha_loop[node * 12 + h] = exl[h] * rden[h];
    }
}

// ---------------- layer-1 aggregation + bias + ELU -> h1 (bf16) ----------------
__global__ __launch_bounds__(256) void agg1_kernel(const unsigned short* __restrict__ hx,
                                                   const unsigned short* __restrict__ alpha_e,
                                                   const float* __restrict__ alpha_loop,
                                                   const int* __restrict__ rowptr,
                                                   const int* __restrict__ src_sorted,
                                                   const void* __restrict__ b1,
                                                   const int* __restrict__ flags,
                                                   unsigned short* __restrict__ h1) {
    int isF32 = flags[0];
    int lane = threadIdx.x & 63;
    int node = blockIdx.x * 4 + (threadIdx.x >> 6);
    if (node >= N_NODES) return;
    int start = rowptr[node], end = rowptr[node + 1];
    if (start < 0) start = 0;
    if (end > N_EDGES) end = N_EDGES;
    float acc[6];
    const unsigned short* hxn = hx + (size_t)node * HC;
#pragma unroll
    for (int j = 0; j < 6; j++) {
        int ch = lane + 64 * j;
        acc[j] = alpha_loop[node * 12 + (ch >> 5)] * bf2f(hxn[ch]);
    }
    for (int p = start; p < end; p++) {
        int s = clampN(src_sorted[p]);
        const unsigned short* hxs = hx + (size_t)s * HC;
#pragma unroll
        for (int j = 0; j < 6; j++) {
            int ch = lane + 64 * j;
            acc[j] += bf2f(alpha_e[(size_t)p * 12 + (ch >> 5)]) * bf2f(hxs[ch]);
        }
    }
#pragma unroll
    for (int j = 0; j < 6; j++) {
        int ch = lane + 64 * j;
        float v = acc[j] + ldf(b1, (size_t)ch, isF32);
        v = v > 0.f ? v : expm1f(v);
        h1[(size_t)node * HC + ch] = f2bf(v);
    }
}

// ---------------- layer-2 aggregation + head-mean + bias + log_softmax ----------------
// OUTPUT IS FLOAT32: d_out = [h2 (800000 f32) | log_softmax (800000 f32)]
__global__ __launch_bounds__(256) void agg2_kernel(const unsigned short* __restrict__ hx,
                                                   const unsigned short* __restrict__ alpha_e,
                                                   const float* __restrict__ alpha_loop,
                                                   const int* __restrict__ rowptr,
                                                   const int* __restrict__ src_sorted,
                                                   const void* __restrict__ b2,
                                                   const int* __restrict__ flags,
                                                   float* __restrict__ out) {
    int isF32 = flags[0];
    int lane = threadIdx.x & 63;
    int node = blockIdx.x * 4 + (threadIdx.x >> 6);
    if (node >= N_NODES) return;
    int start = rowptr[node], end = rowptr[node + 1];
    if (start < 0) start = 0;
    if (end > N_EDGES) end = N_EDGES;
    float acc[6];
    const unsigned short* hxn = hx + (size_t)node * HC;
#pragma unroll
    for (int j = 0; j < 6; j++) {
        int ch = lane + 64 * j;
        acc[j] = alpha_loop[node * 12 + (ch >> 5)] * bf2f(hxn[ch]);
    }
    for (int p = start; p < end; p++) {
        int s = clampN(src_sorted[p]);
        const unsigned short* hxs = hx + (size_t)s * HC;
#pragma unroll
        for (int j = 0; j < 6; j++) {
            int ch = lane + 64 * j;
            acc[j] += bf2f(alpha_e[(size_t)p * 12 + (ch >> 5)]) * bf2f(hxs[ch]);
        }
    }
    float local = acc[0] + acc[1] + acc[2] + acc[3] + acc[4] + acc[5];
    local += __shfl_xor(local, 32);
    int c = lane & 31;
    float h2v = local * (1.f / 12.f) + ldf(b2, (size_t)c, isF32);
    float m = h2v;
#pragma unroll
    for (int off = 1; off < 32; off <<= 1) m = fmaxf(m, __shfl_xor(m, off));
    float s = expf(h2v - m);
#pragma unroll
    for (int off = 1; off < 32; off <<= 1) s += __shfl_xor(s, off);
    float lsm = h2v - m - logf(s);
    if (lane < 32) {
        out[(size_t)node * 32 + c] = h2v;
        out[(size_t)N_NODES * 32 + (size_t)node * 32 + c] = lsm;
    }
}

extern "C" void kernel_launch(void* const* d_in, const int* in_sizes, int n_in,
                              void* d_out, int out_size, void* d_ws, size_t ws_size,
                              hipStream_t stream) {
    const void* x        = d_in[0];
    const void* ei       = d_in[1];
    const void* ea       = d_in[2];
    const void* W1       = d_in[3];
    const void* att_src1 = d_in[4];
    const void* att_dst1 = d_in[5];
    const void* We1      = d_in[6];
    const void* att_e1   = d_in[7];
    const void* b1       = d_in[8];
    const void* W2       = d_in[9];
    const void* att_src2 = d_in[10];
    const void* att_dst2 = d_in[11];
    const void* b2       = d_in[12];
    float* out = (float*)d_out;

    char* ws = (char*)d_ws;
    size_t off = 0;
    auto alloc = [&](size_t bytes) -> void* {
        void* p = ws + off;
        off = (off + bytes + 255) & ~(size_t)255;
        return p;
    };
    int*            flags      = (int*)alloc(16);
    float*          M1         = (float*)alloc((size_t)32 * 12 * 4);
    int*            rowptr     = (int*)alloc((size_t)(N_NODES + 1) * 4);
    int*            cnt        = (int*)alloc((size_t)N_NODES * 4);
    int*            wofs       = (int*)alloc((size_t)N_NODES * 4);
    float*          a_s        = (float*)alloc((size_t)N_NODES * 12 * 4);
    float*          a_d        = (float*)alloc((size_t)N_NODES * 12 * 4);
    float*          alpha_loop = (float*)alloc((size_t)N_NODES * 12 * 4);
    int*            src_sorted = (int*)alloc((size_t)N_EDGES * 4);
    unsigned short* alpha_e    = (unsigned short*)alloc((size_t)N_EDGES * 12 * 2);
    unsigned short* hx         = (unsigned short*)alloc((size_t)N_NODES * HC * 2);
    unsigned short* h1         = (unsigned short*)alloc((size_t)N_NODES * HC * 2);

    hipMemsetAsync(cnt, 0, (size_t)N_NODES * 4, stream);
    detect_kernel<<<1, 256, 0, stream>>>((const unsigned short*)x, (const unsigned int*)ei, flags);
    prep_kernel<<<2, 256, 0, stream>>>(We1, att_e1, flags, M1);
    hist_kernel<<<(N_EDGES + 255) / 256, 256, 0, stream>>>(ei, flags, cnt);
    scan_kernel<<<1, 256, 0, stream>>>(cnt, rowptr, wofs);
    scatter_kernel<<<(N_EDGES + 255) / 256, 256, 0, stream>>>(ei, ea, flags, M1, wofs,
                                                              src_sorted, alpha_e);
    // layer 1
    gemm_valu<<<dim3((N_NODES + 63) / 64, 6), 256, 0, stream>>>(x, W1, flags, 1, hx,
                                                                N_NODES, NFEAT);
    att_kernel<<<(N_NODES * 12 + 255) / 256, 256, 0, stream>>>(hx, att_src1, att_dst1, flags,
                                                               a_s, a_d);
    softmax_kernel<<<(N_NODES + 3) / 4, 256, 0, stream>>>(a_s, a_d, rowptr, src_sorted,
                                                          alpha_e, alpha_loop, 1);
    agg1_kernel<<<(N_NODES + 3) / 4, 256, 0, stream>>>(hx, alpha_e, alpha_loop, rowptr,
                                                       src_sorted, b1, flags, h1);
    // layer 2
    gemm_valu<<<dim3((N_NODES + 63) / 64, 6), 256, 0, stream>>>(h1, W2, flags, 0, hx,
                                                                N_NODES, HC);
    att_kernel<<<(N_NODES * 12 + 255) / 256, 256, 0, stream>>>(hx, att_src2, att_dst2, flags,
                                                               a_s, a_d);
    softmax_kernel<<<(N_NODES + 3) / 4, 256, 0, stream>>>(a_s, a_d, rowptr, src_sorted,
                                                          alpha_e, alpha_loop, 0);
    agg2_kernel<<<(N_NODES + 3) / 4, 256, 0, stream>>>(hx, alpha_e, alpha_loop, rowptr,
                                                       src_sorted, b2, flags, out);
}

// Round 9
// 767.755 us; speedup vs baseline: 1.5996x; 1.5996x over previous
//
#include <hip/hip_runtime.h>
#include <hip/hip_bf16.h>
#include <math.h>

#define N_NODES 25000
#define N_EDGES 400000
#define NFEAT   256
#define NHID    32
#define NHEAD   12
#define HC      384
#define NEG_SLOPE 0.2f

typedef __attribute__((ext_vector_type(8))) short short8;
typedef __attribute__((ext_vector_type(4))) float floatx4;

__device__ __forceinline__ float bf2f(unsigned short u) {
    union { unsigned int i; float f; } v; v.i = ((unsigned int)u) << 16; return v.f;
}
__device__ __forceinline__ unsigned short f2bf(float f) {
    union { float f; unsigned int i; } v; v.f = f;
    unsigned int x = v.i;
    unsigned int r = (x + 0x7FFFu + ((x >> 16) & 1u)) >> 16;
    return (unsigned short)r;
}
__device__ __forceinline__ int clampN(int s) {
    return ((unsigned)s < (unsigned)N_NODES) ? s : 0;
}
__device__ __forceinline__ float ldf(const void* p, size_t i, int isF32) {
    return isF32 ? ((const float*)p)[i] : bf2f(((const unsigned short*)p)[i]);
}
__device__ __forceinline__ int ldi(const void* p, size_t i, int isI64) {
    return isI64 ? (int)((const unsigned int*)p)[2 * i] : ((const int*)p)[i];
}

// ---------------- dtype detection (1 block) ----------------
__global__ void detect_kernel(const unsigned short* __restrict__ xr,
                              const unsigned int* __restrict__ eir,
                              int* __restrict__ flags) {
    __shared__ int sF, sI;
    if (threadIdx.x == 0) { sF = 0; sI = 0; }
    __syncthreads();
    int t = threadIdx.x;
    int cf = 0, ci = 0;
#pragma unroll
    for (int i = 0; i < 4; i++) {
        unsigned short u = xr[2 * (t * 4 + i)];
        int e = (u >> 7) & 0xFF;
        if (e >= 100 && e <= 140) cf++;
        unsigned int v = eir[2 * (t * 4 + i) + 1];
        if (v == 0u) ci++;
    }
    atomicAdd(&sF, cf);
    atomicAdd(&sI, ci);
    __syncthreads();
    if (threadIdx.x == 0) {
        flags[0] = (sF >= 614) ? 0 : 1;   // 1 -> float inputs are f32
        flags[1] = (sI >= 512) ? 1 : 0;   // 1 -> edge_index is i64
    }
}

// ---------------- prep: M1 fold + W1/W2 transpose to bf16 ----------------
__global__ void prep_kernel(const void* __restrict__ We1,
                            const void* __restrict__ att_e,
                            const void* __restrict__ W1,
                            const void* __restrict__ W2,
                            const int* __restrict__ flags,
                            float* __restrict__ M1,
                            unsigned short* __restrict__ Wt1,
                            unsigned short* __restrict__ Wt2) {
    int isF32 = flags[0];
    int id = blockIdx.x * 256 + threadIdx.x;
    if (id < 384) {
        int k = id / 12, h = id % 12;
        float s = 0.f;
        for (int c = 0; c < 32; c++)
            s += ldf(We1, (size_t)k * HC + h * 32 + c, isF32) *
                 ldf(att_e, (size_t)h * 32 + c, isF32);
        M1[k * 12 + h] = s;
        return;
    }
    int id1 = id - 384;
    if (id1 < 384 * 256) {
        int n = id1 / 256, k = id1 % 256;
        Wt1[(size_t)n * 256 + k] = f2bf(ldf(W1, (size_t)k * HC + n, isF32));
        return;
    }
    int id2 = id1 - 384 * 256;
    if (id2 < 384 * 384) {
        int n = id2 / 384, k = id2 % 384;
        Wt2[(size_t)n * 384 + k] = f2bf(ldf(W2, (size_t)k * HC + n, isF32));
    }
}

// ---------------- CSR build ----------------
__global__ void hist_kernel(const void* __restrict__ ei, const int* __restrict__ flags,
                            int* __restrict__ cnt) {
    int isI64 = flags[1];
    int e = blockIdx.x * 256 + threadIdx.x;
    if (e < N_EDGES) {
        int d = clampN(ldi(ei, (size_t)N_EDGES + e, isI64));
        atomicAdd(&cnt[d], 1);
    }
}

__global__ void scan_kernel(const int* __restrict__ cnt, int* __restrict__ rowptr,
                            int* __restrict__ wofs) {
    __shared__ int buf[256];
    __shared__ int carry_s;
    int tid = threadIdx.x;
    if (tid == 0) { rowptr[0] = 0; carry_s = 0; }
    __syncthreads();
    for (int base = 0; base < N_NODES; base += 256) {
        int i = base + tid;
        int v = (i < N_NODES) ? cnt[i] : 0;
        buf[tid] = v;
        __syncthreads();
        for (int offd = 1; offd < 256; offd <<= 1) {
            int t = (tid >= offd) ? buf[tid - offd] : 0;
            __syncthreads();
            buf[tid] += t;
            __syncthreads();
        }
        int incl = buf[tid];
        int carry = carry_s;
        if (i < N_NODES) { rowptr[i + 1] = carry + incl; wofs[i] = carry + incl - v; }
        __syncthreads();
        if (tid == 255) carry_s += buf[255];
        __syncthreads();
    }
}

// minimal scatter: 8 bytes per edge (src, edge_id)
__global__ void scatter_kernel(const void* __restrict__ ei, const int* __restrict__ flags,
                               int* __restrict__ wofs, int2* __restrict__ pairs) {
    int isI64 = flags[1];
    int e = blockIdx.x * 256 + threadIdx.x;
    if (e >= N_EDGES) return;
    int d = clampN(ldi(ei, (size_t)N_EDGES + e, isI64));
    int pos = atomicAdd(&wofs[d], 1);
    if ((unsigned)pos >= (unsigned)N_EDGES) return;
    pairs[pos] = make_int2(clampN(ldi(ei, (size_t)e, isI64)), e);
}

// folded edge attention in COALESCED edge order: ae_edge[e*12+h] = (ea[e,:] . M1[:,h])
__global__ void ae_kernel(const void* __restrict__ ea, const int* __restrict__ flags,
                          const float* __restrict__ M1,
                          unsigned short* __restrict__ ae_edge) {
    __shared__ float sM[384];
    for (int i = threadIdx.x; i < 384; i += 256) sM[i] = M1[i];
    __syncthreads();
    int isF32 = flags[0];
    int e = blockIdx.x * 256 + threadIdx.x;
    if (e >= N_EDGES) return;
    float a[32];
    if (isF32) {
        const float4* r4 = (const float4*)((const float*)ea + (size_t)e * 32);
#pragma unroll
        for (int i = 0; i < 8; i++) {
            float4 v = r4[i];
            a[4 * i] = v.x; a[4 * i + 1] = v.y; a[4 * i + 2] = v.z; a[4 * i + 3] = v.w;
        }
    } else {
        const unsigned short* r = (const unsigned short*)ea + (size_t)e * 32;
#pragma unroll
        for (int i = 0; i < 32; i++) a[i] = bf2f(r[i]);
    }
    float ev[12];
#pragma unroll
    for (int h = 0; h < 12; h++) ev[h] = 0.f;
#pragma unroll
    for (int k = 0; k < 32; k++)
#pragma unroll
        for (int h = 0; h < 12; h++) ev[h] += a[k] * sM[k * 12 + h];
    unsigned int w[6];
#pragma unroll
    for (int i = 0; i < 6; i++)
        w[i] = (unsigned int)f2bf(ev[2 * i]) | ((unsigned int)f2bf(ev[2 * i + 1]) << 16);
    uint2* dst = (uint2*)(ae_edge + (size_t)e * 12);
    dst[0] = make_uint2(w[0], w[1]);
    dst[1] = make_uint2(w[2], w[3]);
    dst[2] = make_uint2(w[4], w[5]);
}

// ---------------- MFMA GEMM: C[M x 384](bf16) = A[M x K] * Wt[384 x K](bf16) ----------------
// A is f32 (converted on the fly) when aFromFlag && flags[0], else bf16.
__global__ __launch_bounds__(256) void gemm_mfma(const void* __restrict__ A,
                                                 const unsigned short* __restrict__ Bt,
                                                 const int* __restrict__ flags,
                                                 int aFromFlag,
                                                 unsigned short* __restrict__ C,
                                                 int M, int K) {
    int aF32 = aFromFlag ? flags[0] : 0;
    int lane = threadIdx.x & 63;
    int w = threadIdx.x >> 6;
    int m0 = (blockIdx.x * 4 + w) * 16;
    int n0 = blockIdx.y * 64;
    int r = lane & 15, q = lane >> 4;
    int row = m0 + r;
    if (row >= M) row = M - 1;
    floatx4 acc[4];
#pragma unroll
    for (int j = 0; j < 4; j++) acc[j] = (floatx4){0.f, 0.f, 0.f, 0.f};
    for (int k0 = 0; k0 < K; k0 += 32) {
        short8 a;
        if (aF32) {
            const float4* ap = (const float4*)((const float*)A + (size_t)row * K + k0 + q * 8);
            float4 u = ap[0], v = ap[1];
            a[0] = (short)f2bf(u.x); a[1] = (short)f2bf(u.y);
            a[2] = (short)f2bf(u.z); a[3] = (short)f2bf(u.w);
            a[4] = (short)f2bf(v.x); a[5] = (short)f2bf(v.y);
            a[6] = (short)f2bf(v.z); a[7] = (short)f2bf(v.w);
        } else {
            a = *(const short8*)((const unsigned short*)A + (size_t)row * K + k0 + q * 8);
        }
#pragma unroll
        for (int j = 0; j < 4; j++) {
            int col = n0 + 16 * j + r;
            short8 b = *(const short8*)(Bt + (size_t)col * K + k0 + q * 8);
            acc[j] = __builtin_amdgcn_mfma_f32_16x16x32_bf16(a, b, acc[j], 0, 0, 0);
        }
    }
#pragma unroll
    for (int j = 0; j < 4; j++) {
        int col = n0 + 16 * j + r;
#pragma unroll
        for (int t = 0; t < 4; t++) {
            int orow = m0 + q * 4 + t;
            if (orow < M) C[(size_t)orow * HC + col] = f2bf(acc[j][t]);
        }
    }
}

// ---------------- per-(node,head) attention logits ----------------
__global__ void att_kernel(const unsigned short* __restrict__ hx,
                           const void* __restrict__ att_src,
                           const void* __restrict__ att_dst,
                           const int* __restrict__ flags,
                           float* __restrict__ a_s, float* __restrict__ a_d) {
    int isF32 = flags[0];
    int id = blockIdx.x * 256 + threadIdx.x;
    if (id >= N_NODES * NHEAD) return;
    int n = id / 12, h = id % 12;
    const unsigned short* row = hx + (size_t)n * HC + h * 32;
    float s = 0.f, d = 0.f;
#pragma unroll
    for (int c = 0; c < 32; c++) {
        float v = bf2f(row[c]);
        s += v * ldf(att_src, (size_t)h * 32 + c, isF32);
        d += v * ldf(att_dst, (size_t)h * 32 + c, isF32);
    }
    a_s[id] = s;
    a_d[id] = d;
}

// ---------------- segment softmax: stores UNNORMALIZED exp + per-node rden ----------------
__global__ __launch_bounds__(256) void softmax_kernel(const float* __restrict__ a_s,
                                                      const float* __restrict__ a_d,
                                                      const int* __restrict__ rowptr,
                                                      const int2* __restrict__ pairs,
                                                      const unsigned short* __restrict__ ae_edge,
                                                      unsigned short* __restrict__ alpha_e,
                                                      float* __restrict__ exl_out,
                                                      float* __restrict__ rden_out,
                                                      int has_ae) {
    int lane = threadIdx.x & 63;
    int node = blockIdx.x * 4 + (threadIdx.x >> 6);
    if (node >= N_NODES) return;
    int start = rowptr[node], end = rowptr[node + 1];
    if (start < 0) start = 0;
    if (end > N_EDGES) end = N_EDGES;
    int deg = end - start;
    float adn[12], asn[12], mx[12], sae[12];
#pragma unroll
    for (int h = 0; h < 12; h++) {
        adn[h] = a_d[node * 12 + h];
        asn[h] = a_s[node * 12 + h];
        mx[h] = -1e30f;
        sae[h] = 0.f;
    }
    float invdeg = 1.f / fmaxf((float)deg, 1.f);

    if (deg <= 64) {
        // -------- fast path: one edge per lane, logits stay in registers --------
        int p = start + lane;
        bool act = p < end;
        int2 pe = act ? pairs[p] : make_int2(0, 0);
        int s = clampN(pe.x);
        int eid = ((unsigned)pe.y < (unsigned)N_EDGES) ? pe.y : 0;
        float ev[12];
        float aev[12];
        if (has_ae && act) {
            const uint2* src = (const uint2*)(ae_edge + (size_t)eid * 12);
            uint2 w0 = src[0], w1 = src[1], w2 = src[2];
            unsigned int ws[6] = {w0.x, w0.y, w1.x, w1.y, w2.x, w2.y};
#pragma unroll
            for (int i = 0; i < 6; i++) {
                aev[2 * i]     = bf2f((unsigned short)(ws[i] & 0xFFFF));
                aev[2 * i + 1] = bf2f((unsigned short)(ws[i] >> 16));
            }
        } else {
#pragma unroll
            for (int h = 0; h < 12; h++) aev[h] = 0.f;
        }
        if (act) {
            const float4* as4 = (const float4*)(a_s + (size_t)s * 12);
            float4 f0 = as4[0], f1 = as4[1], f2 = as4[2];
            float asv[12] = {f0.x, f0.y, f0.z, f0.w, f1.x, f1.y, f1.z, f1.w,
                             f2.x, f2.y, f2.z, f2.w};
#pragma unroll
            for (int h = 0; h < 12; h++) {
                float v = asv[h] + adn[h] + aev[h];
                sae[h] = aev[h];
                v = v > 0.f ? v : NEG_SLOPE * v;
                ev[h] = v;
                mx[h] = v;
            }
        } else {
#pragma unroll
            for (int h = 0; h < 12; h++) ev[h] = -1e30f;
        }
#pragma unroll
        for (int off = 1; off < 64; off <<= 1) {
#pragma unroll
            for (int h = 0; h < 12; h++) {
                mx[h] = fmaxf(mx[h], __shfl_xor(mx[h], off));
                if (has_ae) sae[h] += __shfl_xor(sae[h], off);
            }
        }
        float el[12], den[12], ex[12];
#pragma unroll
        for (int h = 0; h < 12; h++) {
            float v = asn[h] + adn[h] + (has_ae ? sae[h] * invdeg : 0.f);
            v = v > 0.f ? v : NEG_SLOPE * v;
            el[h] = v;
            mx[h] = fmaxf(mx[h], v);
            ex[h] = act ? expf(ev[h] - mx[h]) : 0.f;
            den[h] = ex[h];
        }
#pragma unroll
        for (int off = 1; off < 64; off <<= 1) {
#pragma unroll
            for (int h = 0; h < 12; h++) den[h] += __shfl_xor(den[h], off);
        }
        if (act) {
            unsigned int w[6];
#pragma unroll
            for (int i = 0; i < 6; i++)
                w[i] = (unsigned int)f2bf(ex[2 * i]) | ((unsigned int)f2bf(ex[2 * i + 1]) << 16);
            uint2* dst = (uint2*)(alpha_e + (size_t)p * 12);
            dst[0] = make_uint2(w[0], w[1]);
            dst[1] = make_uint2(w[2], w[3]);
            dst[2] = make_uint2(w[4], w[5]);
        }
        if (lane == 0) {
#pragma unroll
            for (int h = 0; h < 12; h++) {
                float exl = expf(el[h] - mx[h]);
                exl_out[node * 12 + h] = exl;
                rden_out[node * 12 + h] = 1.f / (den[h] + exl);
            }
        }
    } else {
        // -------- generic path (deg > 64): two passes through alpha_e --------
        for (int p = start + lane; p < end; p += 64) {
            int2 pe = pairs[p];
            int s = clampN(pe.x);
            int eid = ((unsigned)pe.y < (unsigned)N_EDGES) ? pe.y : 0;
#pragma unroll
            for (int h = 0; h < 12; h++) {
                float v = a_s[(size_t)s * 12 + h] + adn[h];
                if (has_ae) {
                    float a = bf2f(ae_edge[(size_t)eid * 12 + h]);
                    sae[h] += a;
                    v += a;
                }
                v = v > 0.f ? v : NEG_SLOPE * v;
                alpha_e[(size_t)p * 12 + h] = f2bf(v);
                mx[h] = fmaxf(mx[h], v);
            }
        }
#pragma unroll
        for (int off = 1; off < 64; off <<= 1) {
#pragma unroll
            for (int h = 0; h < 12; h++) {
                mx[h] = fmaxf(mx[h], __shfl_xor(mx[h], off));
                if (has_ae) sae[h] += __shfl_xor(sae[h], off);
            }
        }
        float el[12], den[12];
#pragma unroll
        for (int h = 0; h < 12; h++) {
            float v = asn[h] + adn[h] + (has_ae ? sae[h] * invdeg : 0.f);
            v = v > 0.f ? v : NEG_SLOPE * v;
            el[h] = v;
            mx[h] = fmaxf(mx[h], v);
            den[h] = 0.f;
        }
        for (int p = start + lane; p < end; p += 64) {
#pragma unroll
            for (int h = 0; h < 12; h++) {
                float ex = expf(bf2f(alpha_e[(size_t)p * 12 + h]) - mx[h]);
                alpha_e[(size_t)p * 12 + h] = f2bf(ex);
                den[h] += ex;
            }
        }
#pragma unroll
        for (int off = 1; off < 64; off <<= 1) {
#pragma unroll
            for (int h = 0; h < 12; h++) den[h] += __shfl_xor(den[h], off);
        }
        if (lane == 0) {
#pragma unroll
            for (int h = 0; h < 12; h++) {
                float exl = expf(el[h] - mx[h]);
                exl_out[node * 12 + h] = exl;
                rden_out[node * 12 + h] = 1.f / (den[h] + exl);
            }
        }
    }
}

// ---------------- layer-1 aggregation (rden applied here) + bias + ELU -> h1 ----------------
__global__ __launch_bounds__(256) void agg1_kernel(const unsigned short* __restrict__ hx,
                                                   const unsigned short* __restrict__ alpha_e,
                                                   const float* __restrict__ exl,
                                                   const float* __restrict__ rden,
                                                   const int* __restrict__ rowptr,
                                                   const int2* __restrict__ pairs,
                                                   const void* __restrict__ b1,
                                                   const int* __restrict__ flags,
                                                   unsigned short* __restrict__ h1) {
    int isF32 = flags[0];
    int lane = threadIdx.x & 63;
    int node = blockIdx.x * 4 + (threadIdx.x >> 6);
    if (node >= N_NODES) return;
    int start = rowptr[node], end = rowptr[node + 1];
    if (start < 0) start = 0;
    if (end > N_EDGES) end = N_EDGES;
    float acc[6];
    const unsigned short* hxn = hx + (size_t)node * HC;
#pragma unroll
    for (int j = 0; j < 6; j++) {
        int ch = lane + 64 * j;
        acc[j] = exl[node * 12 + (ch >> 5)] * bf2f(hxn[ch]);
    }
    for (int p = start; p < end; p++) {
        int s = clampN(pairs[p].x);
        const unsigned short* hxs = hx + (size_t)s * HC;
#pragma unroll
        for (int j = 0; j < 6; j++) {
            int ch = lane + 64 * j;
            acc[j] += bf2f(alpha_e[(size_t)p * 12 + (ch >> 5)]) * bf2f(hxs[ch]);
        }
    }
#pragma unroll
    for (int j = 0; j < 6; j++) {
        int ch = lane + 64 * j;
        float v = acc[j] * rden[node * 12 + (ch >> 5)] + ldf(b1, (size_t)ch, isF32);
        v = v > 0.f ? v : expm1f(v);
        h1[(size_t)node * HC + ch] = f2bf(v);
    }
}

// ---------------- layer-2 aggregation + head-mean + bias + log_softmax (f32 out) ----------------
__global__ __launch_bounds__(256) void agg2_kernel(const unsigned short* __restrict__ hx,
                                                   const unsigned short* __restrict__ alpha_e,
                                                   const float* __restrict__ exl,
                                                   const float* __restrict__ rden,
                                                   const int* __restrict__ rowptr,
                                                   const int2* __restrict__ pairs,
                                                   const void* __restrict__ b2,
                                                   const int* __restrict__ flags,
                                                   float* __restrict__ out) {
    int isF32 = flags[0];
    int lane = threadIdx.x & 63;
    int node = blockIdx.x * 4 + (threadIdx.x >> 6);
    if (node >= N_NODES) return;
    int start = rowptr[node], end = rowptr[node + 1];
    if (start < 0) start = 0;
    if (end > N_EDGES) end = N_EDGES;
    float acc[6];
    const unsigned short* hxn = hx + (size_t)node * HC;
#pragma unroll
    for (int j = 0; j < 6; j++) {
        int ch = lane + 64 * j;
        acc[j] = exl[node * 12 + (ch >> 5)] * bf2f(hxn[ch]);
    }
    for (int p = start; p < end; p++) {
        int s = clampN(pairs[p].x);
        const unsigned short* hxs = hx + (size_t)s * HC;
#pragma unroll
        for (int j = 0; j < 6; j++) {
            int ch = lane + 64 * j;
            acc[j] += bf2f(alpha_e[(size_t)p * 12 + (ch >> 5)]) * bf2f(hxs[ch]);
        }
    }
    float local = 0.f;
#pragma unroll
    for (int j = 0; j < 6; j++) {
        int ch = lane + 64 * j;
        local += acc[j] * rden[node * 12 + (ch >> 5)];
    }
    local += __shfl_xor(local, 32);
    int c = lane & 31;
    float h2v = local * (1.f / 12.f) + ldf(b2, (size_t)c, isF32);
    float m = h2v;
#pragma unroll
    for (int off = 1; off < 32; off <<= 1) m = fmaxf(m, __shfl_xor(m, off));
    float s = expf(h2v - m);
#pragma unroll
    for (int off = 1; off < 32; off <<= 1) s += __shfl_xor(s, off);
    float lsm = h2v - m - logf(s);
    if (lane < 32) {
        out[(size_t)node * 32 + c] = h2v;
        out[(size_t)N_NODES * 32 + (size_t)node * 32 + c] = lsm;
    }
}

extern "C" void kernel_launch(void* const* d_in, const int* in_sizes, int n_in,
                              void* d_out, int out_size, void* d_ws, size_t ws_size,
                              hipStream_t stream) {
    const void* x        = d_in[0];
    const void* ei       = d_in[1];
    const void* ea       = d_in[2];
    const void* W1       = d_in[3];
    const void* att_src1 = d_in[4];
    const void* att_dst1 = d_in[5];
    const void* We1      = d_in[6];
    const void* att_e1   = d_in[7];
    const void* b1       = d_in[8];
    const void* W2       = d_in[9];
    const void* att_src2 = d_in[10];
    const void* att_dst2 = d_in[11];
    const void* b2       = d_in[12];
    float* out = (float*)d_out;

    char* ws = (char*)d_ws;
    size_t off = 0;
    auto alloc = [&](size_t bytes) -> void* {
        void* p = ws + off;
        off = (off + bytes + 255) & ~(size_t)255;
        return p;
    };
    int*            flags   = (int*)alloc(16);
    float*          M1      = (float*)alloc((size_t)384 * 4);
    int*            rowptr  = (int*)alloc((size_t)(N_NODES + 1) * 4);
    int*            cnt     = (int*)alloc((size_t)N_NODES * 4);
    int*            wofs    = (int*)alloc((size_t)N_NODES * 4);
    float*          a_s     = (float*)alloc((size_t)N_NODES * 12 * 4);
    float*          a_d     = (float*)alloc((size_t)N_NODES * 12 * 4);
    float*          exl     = (float*)alloc((size_t)N_NODES * 12 * 4);
    float*          rden    = (float*)alloc((size_t)N_NODES * 12 * 4);
    int2*           pairs   = (int2*)alloc((size_t)N_EDGES * 8);
    unsigned short* alpha_e = (unsigned short*)alloc((size_t)N_EDGES * 12 * 2);
    unsigned short* hx      = (unsigned short*)alloc((size_t)N_NODES * HC * 2);
    // h1 aliases ae_edge: ae_edge dead after softmax1, h1 born in agg1 (after).
    unsigned short* h1      = (unsigned short*)alloc((size_t)N_NODES * HC * 2);
    unsigned short* ae_edge = h1;
    unsigned short* Wt1     = (unsigned short*)alloc((size_t)384 * 256 * 2);
    unsigned short* Wt2     = (unsigned short*)alloc((size_t)384 * 384 * 2);

    hipMemsetAsync(cnt, 0, (size_t)N_NODES * 4, stream);
    detect_kernel<<<1, 256, 0, stream>>>((const unsigned short*)x, (const unsigned int*)ei, flags);
    prep_kernel<<<(384 + 384 * 256 + 384 * 384 + 255) / 256, 256, 0, stream>>>(
        We1, att_e1, W1, W2, flags, M1, Wt1, Wt2);
    hist_kernel<<<(N_EDGES + 255) / 256, 256, 0, stream>>>(ei, flags, cnt);
    scan_kernel<<<1, 256, 0, stream>>>(cnt, rowptr, wofs);
    scatter_kernel<<<(N_EDGES + 255) / 256, 256, 0, stream>>>(ei, flags, wofs, pairs);
    ae_kernel<<<(N_EDGES + 255) / 256, 256, 0, stream>>>(ea, flags, M1, ae_edge);
    // layer 1
    gemm_mfma<<<dim3((N_NODES + 63) / 64, 6), 256, 0, stream>>>(x, Wt1, flags, 1, hx,
                                                                N_NODES, NFEAT);
    att_kernel<<<(N_NODES * 12 + 255) / 256, 256, 0, stream>>>(hx, att_src1, att_dst1, flags,
                                                               a_s, a_d);
    softmax_kernel<<<(N_NODES + 3) / 4, 256, 0, stream>>>(a_s, a_d, rowptr, pairs, ae_edge,
                                                          alpha_e, exl, rden, 1);
    agg1_kernel<<<(N_NODES + 3) / 4, 256, 0, stream>>>(hx, alpha_e, exl, rden, rowptr, pairs,
                                                       b1, flags, h1);
    // layer 2
    gemm_mfma<<<dim3((N_NODES + 63) / 64, 6), 256, 0, stream>>>(h1, Wt2, flags, 0, hx,
                                                                N_NODES, HC);
    att_kernel<<<(N_NODES * 12 + 255) / 256, 256, 0, stream>>>(hx, att_src2, att_dst2, flags,
                                                               a_s, a_d);
    softmax_kernel<<<(N_NODES + 3) / 4, 256, 0, stream>>>(a_s, a_d, rowptr, pairs, ae_edge,
                                                          alpha_e, exl, rden, 0);
    agg2_kernel<<<(N_NODES + 3) / 4, 256, 0, stream>>>(hx, alpha_e, exl, rden, rowptr, pairs,
                                                       b2, flags, out);
}

// Round 10
// 668.929 us; speedup vs baseline: 1.8360x; 1.1477x over previous
//
#include <hip/hip_runtime.h>
#include <hip/hip_bf16.h>
#include <math.h>

#define N_NODES 25000
#define N_EDGES 400000
#define NFEAT   256
#define NHID    32
#define NHEAD   12
#define HC      384
#define NEG_SLOPE 0.2f
#define NBLK    ((N_NODES + 255) / 256)

typedef __attribute__((ext_vector_type(8))) short short8;
typedef __attribute__((ext_vector_type(4))) float floatx4;

__device__ __forceinline__ float bf2f(unsigned short u) {
    union { unsigned int i; float f; } v; v.i = ((unsigned int)u) << 16; return v.f;
}
__device__ __forceinline__ unsigned short f2bf(float f) {
    union { float f; unsigned int i; } v; v.f = f;
    unsigned int x = v.i;
    unsigned int r = (x + 0x7FFFu + ((x >> 16) & 1u)) >> 16;
    return (unsigned short)r;
}
__device__ __forceinline__ int clampN(int s) {
    return ((unsigned)s < (unsigned)N_NODES) ? s : 0;
}
__device__ __forceinline__ float ldf(const void* p, size_t i, int isF32) {
    return isF32 ? ((const float*)p)[i] : bf2f(((const unsigned short*)p)[i]);
}
__device__ __forceinline__ int ldi(const void* p, size_t i, int isI64) {
    return isI64 ? (int)((const unsigned int*)p)[2 * i] : ((const int*)p)[i];
}

// ---------------- dtype detection (1 block) ----------------
__global__ void detect_kernel(const unsigned short* __restrict__ xr,
                              const unsigned int* __restrict__ eir,
                              int* __restrict__ flags) {
    __shared__ int sF, sI;
    if (threadIdx.x == 0) { sF = 0; sI = 0; }
    __syncthreads();
    int t = threadIdx.x;
    int cf = 0, ci = 0;
#pragma unroll
    for (int i = 0; i < 4; i++) {
        unsigned short u = xr[2 * (t * 4 + i)];
        int e = (u >> 7) & 0xFF;
        if (e >= 100 && e <= 140) cf++;
        unsigned int v = eir[2 * (t * 4 + i) + 1];
        if (v == 0u) ci++;
    }
    atomicAdd(&sF, cf);
    atomicAdd(&sI, ci);
    __syncthreads();
    if (threadIdx.x == 0) {
        flags[0] = (sF >= 614) ? 0 : 1;   // 1 -> float inputs are f32
        flags[1] = (sI >= 512) ? 1 : 0;   // 1 -> edge_index is i64
    }
}

// ---------------- prep: M1 fold + W1/W2 transpose to bf16 ----------------
__global__ void prep_kernel(const void* __restrict__ We1,
                            const void* __restrict__ att_e,
                            const void* __restrict__ W1,
                            const void* __restrict__ W2,
                            const int* __restrict__ flags,
                            float* __restrict__ M1,
                            unsigned short* __restrict__ Wt1,
                            unsigned short* __restrict__ Wt2) {
    int isF32 = flags[0];
    int id = blockIdx.x * 256 + threadIdx.x;
    if (id < 384) {
        int k = id / 12, h = id % 12;
        float s = 0.f;
        for (int c = 0; c < 32; c++)
            s += ldf(We1, (size_t)k * HC + h * 32 + c, isF32) *
                 ldf(att_e, (size_t)h * 32 + c, isF32);
        M1[k * 12 + h] = s;
        return;
    }
    int id1 = id - 384;
    if (id1 < 384 * 256) {
        int n = id1 / 256, k = id1 % 256;
        Wt1[(size_t)n * 256 + k] = f2bf(ldf(W1, (size_t)k * HC + n, isF32));
        return;
    }
    int id2 = id1 - 384 * 256;
    if (id2 < 384 * 384) {
        int n = id2 / 384, k = id2 % 384;
        Wt2[(size_t)n * 384 + k] = f2bf(ldf(W2, (size_t)k * HC + n, isF32));
    }
}

// ---------------- CSR build ----------------
__global__ void hist_kernel(const void* __restrict__ ei, const int* __restrict__ flags,
                            int* __restrict__ cnt) {
    int isI64 = flags[1];
    int e = blockIdx.x * 256 + threadIdx.x;
    if (e < N_EDGES) {
        int d = clampN(ldi(ei, (size_t)N_EDGES + e, isI64));
        atomicAdd(&cnt[d], 1);
    }
}

// 3-phase device-wide scan (replaces the 109 us single-block scan)
__global__ void blockscan_kernel(const int* __restrict__ cnt, int* __restrict__ incl,
                                 int* __restrict__ bsum) {
    __shared__ int buf[256];
    int i = blockIdx.x * 256 + threadIdx.x;
    int v = (i < N_NODES) ? cnt[i] : 0;
    buf[threadIdx.x] = v;
    __syncthreads();
    for (int off = 1; off < 256; off <<= 1) {
        int t = (threadIdx.x >= off) ? buf[threadIdx.x - off] : 0;
        __syncthreads();
        buf[threadIdx.x] += t;
        __syncthreads();
    }
    if (i < N_NODES) incl[i] = buf[threadIdx.x];
    if (threadIdx.x == 255) bsum[blockIdx.x] = buf[255];
}

__global__ void bscan_kernel(const int* __restrict__ bsum, int* __restrict__ boff) {
    __shared__ int buf[128];
    int t = threadIdx.x;
    int v = (t < NBLK) ? bsum[t] : 0;
    buf[t] = v;
    __syncthreads();
    for (int off = 1; off < 128; off <<= 1) {
        int u = (t >= off) ? buf[t - off] : 0;
        __syncthreads();
        buf[t] += u;
        __syncthreads();
    }
    if (t < NBLK) boff[t] = buf[t] - v;   // exclusive prefix of block sums
}

__global__ void finalize_kernel(const int* __restrict__ incl, const int* __restrict__ boff,
                                const int* __restrict__ cnt,
                                int* __restrict__ rowptr, int* __restrict__ wofs) {
    int i = blockIdx.x * 256 + threadIdx.x;
    if (i == 0) rowptr[0] = 0;
    if (i < N_NODES) {
        int v = incl[i] + boff[blockIdx.x];
        rowptr[i + 1] = v;
        wofs[i] = v - cnt[i];
    }
}

// minimal scatter: 8 bytes per edge (src, edge_id)
__global__ void scatter_kernel(const void* __restrict__ ei, const int* __restrict__ flags,
                               int* __restrict__ wofs, int2* __restrict__ pairs) {
    int isI64 = flags[1];
    int e = blockIdx.x * 256 + threadIdx.x;
    if (e >= N_EDGES) return;
    int d = clampN(ldi(ei, (size_t)N_EDGES + e, isI64));
    int pos = atomicAdd(&wofs[d], 1);
    if ((unsigned)pos >= (unsigned)N_EDGES) return;
    pairs[pos] = make_int2(clampN(ldi(ei, (size_t)e, isI64)), e);
}

// folded edge attention in COALESCED edge order: ae_edge[e*12+h] = (ea[e,:] . M1[:,h])
__global__ void ae_kernel(const void* __restrict__ ea, const int* __restrict__ flags,
                          const float* __restrict__ M1,
                          unsigned short* __restrict__ ae_edge) {
    __shared__ float sM[384];
    for (int i = threadIdx.x; i < 384; i += 256) sM[i] = M1[i];
    __syncthreads();
    int isF32 = flags[0];
    int e = blockIdx.x * 256 + threadIdx.x;
    if (e >= N_EDGES) return;
    float a[32];
    if (isF32) {
        const float4* r4 = (const float4*)((const float*)ea + (size_t)e * 32);
#pragma unroll
        for (int i = 0; i < 8; i++) {
            float4 v = r4[i];
            a[4 * i] = v.x; a[4 * i + 1] = v.y; a[4 * i + 2] = v.z; a[4 * i + 3] = v.w;
        }
    } else {
        const unsigned short* r = (const unsigned short*)ea + (size_t)e * 32;
#pragma unroll
        for (int i = 0; i < 32; i++) a[i] = bf2f(r[i]);
    }
    float ev[12];
#pragma unroll
    for (int h = 0; h < 12; h++) ev[h] = 0.f;
#pragma unroll
    for (int k = 0; k < 32; k++)
#pragma unroll
        for (int h = 0; h < 12; h++) ev[h] += a[k] * sM[k * 12 + h];
    unsigned int w[6];
#pragma unroll
    for (int i = 0; i < 6; i++)
        w[i] = (unsigned int)f2bf(ev[2 * i]) | ((unsigned int)f2bf(ev[2 * i + 1]) << 16);
    uint2* dst = (uint2*)(ae_edge + (size_t)e * 12);
    dst[0] = make_uint2(w[0], w[1]);
    dst[1] = make_uint2(w[2], w[3]);
    dst[2] = make_uint2(w[4], w[5]);
}

// ---------------- MFMA GEMM: C[M x 384](bf16) = A[M x K] * Wt[384 x K](bf16) ----------------
__global__ __launch_bounds__(256) void gemm_mfma(const void* __restrict__ A,
                                                 const unsigned short* __restrict__ Bt,
                                                 const int* __restrict__ flags,
                                                 int aFromFlag,
                                                 unsigned short* __restrict__ C,
                                                 int M, int K) {
    int aF32 = aFromFlag ? flags[0] : 0;
    int lane = threadIdx.x & 63;
    int w = threadIdx.x >> 6;
    int m0 = (blockIdx.x * 4 + w) * 16;
    int n0 = blockIdx.y * 64;
    int r = lane & 15, q = lane >> 4;
    int row = m0 + r;
    if (row >= M) row = M - 1;
    floatx4 acc[4];
#pragma unroll
    for (int j = 0; j < 4; j++) acc[j] = (floatx4){0.f, 0.f, 0.f, 0.f};
    for (int k0 = 0; k0 < K; k0 += 32) {
        short8 a;
        if (aF32) {
            const float4* ap = (const float4*)((const float*)A + (size_t)row * K + k0 + q * 8);
            float4 u = ap[0], v = ap[1];
            a[0] = (short)f2bf(u.x); a[1] = (short)f2bf(u.y);
            a[2] = (short)f2bf(u.z); a[3] = (short)f2bf(u.w);
            a[4] = (short)f2bf(v.x); a[5] = (short)f2bf(v.y);
            a[6] = (short)f2bf(v.z); a[7] = (short)f2bf(v.w);
        } else {
            a = *(const short8*)((const unsigned short*)A + (size_t)row * K + k0 + q * 8);
        }
#pragma unroll
        for (int j = 0; j < 4; j++) {
            int col = n0 + 16 * j + r;
            short8 b = *(const short8*)(Bt + (size_t)col * K + k0 + q * 8);
            acc[j] = __builtin_amdgcn_mfma_f32_16x16x32_bf16(a, b, acc[j], 0, 0, 0);
        }
    }
#pragma unroll
    for (int j = 0; j < 4; j++) {
        int col = n0 + 16 * j + r;
#pragma unroll
        for (int t = 0; t < 4; t++) {
            int orow = m0 + q * 4 + t;
            if (orow < M) C[(size_t)orow * HC + col] = f2bf(acc[j][t]);
        }
    }
}

// ---------------- per-(node,head) attention logits ----------------
__global__ void att_kernel(const unsigned short* __restrict__ hx,
                           const void* __restrict__ att_src,
                           const void* __restrict__ att_dst,
                           const int* __restrict__ flags,
                           float* __restrict__ a_s, float* __restrict__ a_d) {
    int isF32 = flags[0];
    int id = blockIdx.x * 256 + threadIdx.x;
    if (id >= N_NODES * NHEAD) return;
    int n = id / 12, h = id % 12;
    const unsigned short* row = hx + (size_t)n * HC + h * 32;
    float s = 0.f, d = 0.f;
#pragma unroll
    for (int c = 0; c < 32; c++) {
        float v = bf2f(row[c]);
        s += v * ldf(att_src, (size_t)h * 32 + c, isF32);
        d += v * ldf(att_dst, (size_t)h * 32 + c, isF32);
    }
    a_s[id] = s;
    a_d[id] = d;
}

// ---------------- segment softmax: stores UNNORMALIZED exp + per-node rden ----------------
__global__ __launch_bounds__(256) void softmax_kernel(const float* __restrict__ a_s,
                                                      const float* __restrict__ a_d,
                                                      const int* __restrict__ rowptr,
                                                      const int2* __restrict__ pairs,
                                                      const unsigned short* __restrict__ ae_edge,
                                                      unsigned short* __restrict__ alpha_e,
                                                      float* __restrict__ exl_out,
                                                      float* __restrict__ rden_out,
                                                      int has_ae) {
    int lane = threadIdx.x & 63;
    int node = blockIdx.x * 4 + (threadIdx.x >> 6);
    if (node >= N_NODES) return;
    int start = rowptr[node], end = rowptr[node + 1];
    if (start < 0) start = 0;
    if (end > N_EDGES) end = N_EDGES;
    int deg = end - start;
    float adn[12], asn[12], mx[12], sae[12];
#pragma unroll
    for (int h = 0; h < 12; h++) {
        adn[h] = a_d[node * 12 + h];
        asn[h] = a_s[node * 12 + h];
        mx[h] = -1e30f;
        sae[h] = 0.f;
    }
    float invdeg = 1.f / fmaxf((float)deg, 1.f);

    if (deg <= 64) {
        int p = start + lane;
        bool act = p < end;
        int2 pe = act ? pairs[p] : make_int2(0, 0);
        int s = clampN(pe.x);
        int eid = ((unsigned)pe.y < (unsigned)N_EDGES) ? pe.y : 0;
        float ev[12];
        float aev[12];
        if (has_ae && act) {
            const uint2* src = (const uint2*)(ae_edge + (size_t)eid * 12);
            uint2 w0 = src[0], w1 = src[1], w2 = src[2];
            unsigned int ws[6] = {w0.x, w0.y, w1.x, w1.y, w2.x, w2.y};
#pragma unroll
            for (int i = 0; i < 6; i++) {
                aev[2 * i]     = bf2f((unsigned short)(ws[i] & 0xFFFF));
                aev[2 * i + 1] = bf2f((unsigned short)(ws[i] >> 16));
            }
        } else {
#pragma unroll
            for (int h = 0; h < 12; h++) aev[h] = 0.f;
        }
        if (act) {
            const float4* as4 = (const float4*)(a_s + (size_t)s * 12);
            float4 f0 = as4[0], f1 = as4[1], f2 = as4[2];
            float asv[12] = {f0.x, f0.y, f0.z, f0.w, f1.x, f1.y, f1.z, f1.w,
                             f2.x, f2.y, f2.z, f2.w};
#pragma unroll
            for (int h = 0; h < 12; h++) {
                float v = asv[h] + adn[h] + aev[h];
                sae[h] = aev[h];
                v = v > 0.f ? v : NEG_SLOPE * v;
                ev[h] = v;
                mx[h] = v;
            }
        } else {
#pragma unroll
            for (int h = 0; h < 12; h++) ev[h] = -1e30f;
        }
#pragma unroll
        for (int off = 1; off < 64; off <<= 1) {
#pragma unroll
            for (int h = 0; h < 12; h++) {
                mx[h] = fmaxf(mx[h], __shfl_xor(mx[h], off));
                if (has_ae) sae[h] += __shfl_xor(sae[h], off);
            }
        }
        float el[12], den[12], ex[12];
#pragma unroll
        for (int h = 0; h < 12; h++) {
            float v = asn[h] + adn[h] + (has_ae ? sae[h] * invdeg : 0.f);
            v = v > 0.f ? v : NEG_SLOPE * v;
            el[h] = v;
            mx[h] = fmaxf(mx[h], v);
            ex[h] = act ? expf(ev[h] - mx[h]) : 0.f;
            den[h] = ex[h];
        }
#pragma unroll
        for (int off = 1; off < 64; off <<= 1) {
#pragma unroll
            for (int h = 0; h < 12; h++) den[h] += __shfl_xor(den[h], off);
        }
        if (act) {
            unsigned int w[6];
#pragma unroll
            for (int i = 0; i < 6; i++)
                w[i] = (unsigned int)f2bf(ex[2 * i]) | ((unsigned int)f2bf(ex[2 * i + 1]) << 16);
            uint2* dst = (uint2*)(alpha_e + (size_t)p * 12);
            dst[0] = make_uint2(w[0], w[1]);
            dst[1] = make_uint2(w[2], w[3]);
            dst[2] = make_uint2(w[4], w[5]);
        }
        if (lane == 0) {
#pragma unroll
            for (int h = 0; h < 12; h++) {
                float exl = expf(el[h] - mx[h]);
                exl_out[node * 12 + h] = exl;
                rden_out[node * 12 + h] = 1.f / (den[h] + exl);
            }
        }
    } else {
        for (int p = start + lane; p < end; p += 64) {
            int2 pe = pairs[p];
            int s = clampN(pe.x);
            int eid = ((unsigned)pe.y < (unsigned)N_EDGES) ? pe.y : 0;
#pragma unroll
            for (int h = 0; h < 12; h++) {
                float v = a_s[(size_t)s * 12 + h] + adn[h];
                if (has_ae) {
                    float a = bf2f(ae_edge[(size_t)eid * 12 + h]);
                    sae[h] += a;
                    v += a;
                }
                v = v > 0.f ? v : NEG_SLOPE * v;
                alpha_e[(size_t)p * 12 + h] = f2bf(v);
                mx[h] = fmaxf(mx[h], v);
            }
        }
#pragma unroll
        for (int off = 1; off < 64; off <<= 1) {
#pragma unroll
            for (int h = 0; h < 12; h++) {
                mx[h] = fmaxf(mx[h], __shfl_xor(mx[h], off));
                if (has_ae) sae[h] += __shfl_xor(sae[h], off);
            }
        }
        float el[12], den[12];
#pragma unroll
        for (int h = 0; h < 12; h++) {
            float v = asn[h] + adn[h] + (has_ae ? sae[h] * invdeg : 0.f);
            v = v > 0.f ? v : NEG_SLOPE * v;
            el[h] = v;
            mx[h] = fmaxf(mx[h], v);
            den[h] = 0.f;
        }
        for (int p = start + lane; p < end; p += 64) {
#pragma unroll
            for (int h = 0; h < 12; h++) {
                float ex = expf(bf2f(alpha_e[(size_t)p * 12 + h]) - mx[h]);
                alpha_e[(size_t)p * 12 + h] = f2bf(ex);
                den[h] += ex;
            }
        }
#pragma unroll
        for (int off = 1; off < 64; off <<= 1) {
#pragma unroll
            for (int h = 0; h < 12; h++) den[h] += __shfl_xor(den[h], off);
        }
        if (lane == 0) {
#pragma unroll
            for (int h = 0; h < 12; h++) {
                float exl = expf(el[h] - mx[h]);
                exl_out[node * 12 + h] = exl;
                rden_out[node * 12 + h] = 1.f / (den[h] + exl);
            }
        }
    }
}

// ---------------- layer-1 aggregation (rden applied here) + bias + ELU -> h1 ----------------
__global__ __launch_bounds__(256) void agg1_kernel(const unsigned short* __restrict__ hx,
                                                   const unsigned short* __restrict__ alpha_e,
                                                   const float* __restrict__ exl,
                                                   const float* __restrict__ rden,
                                                   const int* __restrict__ rowptr,
                                                   const int2* __restrict__ pairs,
                                                   const void* __restrict__ b1,
                                                   const int* __restrict__ flags,
                                                   unsigned short* __restrict__ h1) {
    int isF32 = flags[0];
    int lane = threadIdx.x & 63;
    int node = blockIdx.x * 4 + (threadIdx.x >> 6);
    if (node >= N_NODES) return;
    int start = rowptr[node], end = rowptr[node + 1];
    if (start < 0) start = 0;
    if (end > N_EDGES) end = N_EDGES;
    float acc[6];
    const unsigned short* hxn = hx + (size_t)node * HC;
#pragma unroll
    for (int j = 0; j < 6; j++) {
        int ch = lane + 64 * j;
        acc[j] = exl[node * 12 + (ch >> 5)] * bf2f(hxn[ch]);
    }
    for (int p = start; p < end; p++) {
        int s = clampN(pairs[p].x);
        const unsigned short* hxs = hx + (size_t)s * HC;
#pragma unroll
        for (int j = 0; j < 6; j++) {
            int ch = lane + 64 * j;
            acc[j] += bf2f(alpha_e[(size_t)p * 12 + (ch >> 5)]) * bf2f(hxs[ch]);
        }
    }
#pragma unroll
    for (int j = 0; j < 6; j++) {
        int ch = lane + 64 * j;
        float v = acc[j] * rden[node * 12 + (ch >> 5)] + ldf(b1, (size_t)ch, isF32);
        v = v > 0.f ? v : expm1f(v);
        h1[(size_t)node * HC + ch] = f2bf(v);
    }
}

// ---------------- layer-2 aggregation + head-mean + bias + log_softmax (f32 out) ----------------
__global__ __launch_bounds__(256) void agg2_kernel(const unsigned short* __restrict__ hx,
                                                   const unsigned short* __restrict__ alpha_e,
                                                   const float* __restrict__ exl,
                                                   const float* __restrict__ rden,
                                                   const int* __restrict__ rowptr,
                                                   const int2* __restrict__ pairs,
                                                   const void* __restrict__ b2,
                                                   const int* __restrict__ flags,
                                                   float* __restrict__ out) {
    int isF32 = flags[0];
    int lane = threadIdx.x & 63;
    int node = blockIdx.x * 4 + (threadIdx.x >> 6);
    if (node >= N_NODES) return;
    int start = rowptr[node], end = rowptr[node + 1];
    if (start < 0) start = 0;
    if (end > N_EDGES) end = N_EDGES;
    float acc[6];
    const unsigned short* hxn = hx + (size_t)node * HC;
#pragma unroll
    for (int j = 0; j < 6; j++) {
        int ch = lane + 64 * j;
        acc[j] = exl[node * 12 + (ch >> 5)] * bf2f(hxn[ch]);
    }
    for (int p = start; p < end; p++) {
        int s = clampN(pairs[p].x);
        const unsigned short* hxs = hx + (size_t)s * HC;
#pragma unroll
        for (int j = 0; j < 6; j++) {
            int ch = lane + 64 * j;
            acc[j] += bf2f(alpha_e[(size_t)p * 12 + (ch >> 5)]) * bf2f(hxs[ch]);
        }
    }
    float local = 0.f;
#pragma unroll
    for (int j = 0; j < 6; j++) {
        int ch = lane + 64 * j;
        local += acc[j] * rden[node * 12 + (ch >> 5)];
    }
    local += __shfl_xor(local, 32);
    int c = lane & 31;
    float h2v = local * (1.f / 12.f) + ldf(b2, (size_t)c, isF32);
    float m = h2v;
#pragma unroll
    for (int off = 1; off < 32; off <<= 1) m = fmaxf(m, __shfl_xor(m, off));
    float s = expf(h2v - m);
#pragma unroll
    for (int off = 1; off < 32; off <<= 1) s += __shfl_xor(s, off);
    float lsm = h2v - m - logf(s);
    if (lane < 32) {
        out[(size_t)node * 32 + c] = h2v;
        out[(size_t)N_NODES * 32 + (size_t)node * 32 + c] = lsm;
    }
}

extern "C" void kernel_launch(void* const* d_in, const int* in_sizes, int n_in,
                              void* d_out, int out_size, void* d_ws, size_t ws_size,
                              hipStream_t stream) {
    const void* x        = d_in[0];
    const void* ei       = d_in[1];
    const void* ea       = d_in[2];
    const void* W1       = d_in[3];
    const void* att_src1 = d_in[4];
    const void* att_dst1 = d_in[5];
    const void* We1      = d_in[6];
    const void* att_e1   = d_in[7];
    const void* b1       = d_in[8];
    const void* W2       = d_in[9];
    const void* att_src2 = d_in[10];
    const void* att_dst2 = d_in[11];
    const void* b2       = d_in[12];
    float* out = (float*)d_out;

    char* ws = (char*)d_ws;
    size_t off = 0;
    auto alloc = [&](size_t bytes) -> void* {
        void* p = ws + off;
        off = (off + bytes + 255) & ~(size_t)255;
        return p;
    };
    int*            flags   = (int*)alloc(16);
    float*          M1      = (float*)alloc((size_t)384 * 4);
    int*            rowptr  = (int*)alloc((size_t)(N_NODES + 1) * 4);
    int*            cnt     = (int*)alloc((size_t)N_NODES * 4);
    int*            wofs    = (int*)alloc((size_t)N_NODES * 4);
    int*            incl    = (int*)alloc((size_t)N_NODES * 4);
    int*            bsum    = (int*)alloc((size_t)NBLK * 4);
    int*            boff    = (int*)alloc((size_t)NBLK * 4);
    float*          a_s     = (float*)alloc((size_t)N_NODES * 12 * 4);
    float*          a_d     = (float*)alloc((size_t)N_NODES * 12 * 4);
    float*          exl     = (float*)alloc((size_t)N_NODES * 12 * 4);
    float*          rden    = (float*)alloc((size_t)N_NODES * 12 * 4);
    int2*           pairs   = (int2*)alloc((size_t)N_EDGES * 8);
    unsigned short* alpha_e = (unsigned short*)alloc((size_t)N_EDGES * 12 * 2);
    unsigned short* hx      = (unsigned short*)alloc((size_t)N_NODES * HC * 2);
    // h1 aliases ae_edge: ae_edge dead after softmax1, h1 born in agg1 (after).
    unsigned short* h1      = (unsigned short*)alloc((size_t)N_NODES * HC * 2);
    unsigned short* ae_edge = h1;
    unsigned short* Wt1     = (unsigned short*)alloc((size_t)384 * 256 * 2);
    unsigned short* Wt2     = (unsigned short*)alloc((size_t)384 * 384 * 2);

    hipMemsetAsync(cnt, 0, (size_t)N_NODES * 4, stream);
    detect_kernel<<<1, 256, 0, stream>>>((const unsigned short*)x, (const unsigned int*)ei, flags);
    prep_kernel<<<(384 + 384 * 256 + 384 * 384 + 255) / 256, 256, 0, stream>>>(
        We1, att_e1, W1, W2, flags, M1, Wt1, Wt2);
    hist_kernel<<<(N_EDGES + 255) / 256, 256, 0, stream>>>(ei, flags, cnt);
    blockscan_kernel<<<NBLK, 256, 0, stream>>>(cnt, incl, bsum);
    bscan_kernel<<<1, 128, 0, stream>>>(bsum, boff);
    finalize_kernel<<<NBLK, 256, 0, stream>>>(incl, boff, cnt, rowptr, wofs);
    scatter_kernel<<<(N_EDGES + 255) / 256, 256, 0, stream>>>(ei, flags, wofs, pairs);
    ae_kernel<<<(N_EDGES + 255) / 256, 256, 0, stream>>>(ea, flags, M1, ae_edge);
    // layer 1
    gemm_mfma<<<dim3((N_NODES + 63) / 64, 6), 256, 0, stream>>>(x, Wt1, flags, 1, hx,
                                                                N_NODES, NFEAT);
    att_kernel<<<(N_NODES * 12 + 255) / 256, 256, 0, stream>>>(hx, att_src1, att_dst1, flags,
                                                               a_s, a_d);
    softmax_kernel<<<(N_NODES + 3) / 4, 256, 0, stream>>>(a_s, a_d, rowptr, pairs, ae_edge,
                                                          alpha_e, exl, rden, 1);
    agg1_kernel<<<(N_NODES + 3) / 4, 256, 0, stream>>>(hx, alpha_e, exl, rden, rowptr, pairs,
                                                       b1, flags, h1);
    // layer 2
    gemm_mfma<<<dim3((N_NODES + 63) / 64, 6), 256, 0, stream>>>(h1, Wt2, flags, 0, hx,
                                                                N_NODES, HC);
    att_kernel<<<(N_NODES * 12 + 255) / 256, 256, 0, stream>>>(hx, att_src2, att_dst2, flags,
                                                               a_s, a_d);
    softmax_kernel<<<(N_NODES + 3) / 4, 256, 0, stream>>>(a_s, a_d, rowptr, pairs, ae_edge,
                                                          alpha_e, exl, rden, 0);
    agg2_kernel<<<(N_NODES + 3) / 4, 256, 0, stream>>>(hx, alpha_e, exl, rden, rowptr, pairs,
                                                       b2, flags, out);
}

// Round 11
// 587.116 us; speedup vs baseline: 2.0918x; 1.1393x over previous
//
#include <hip/hip_runtime.h>
#include <hip/hip_bf16.h>
#include <math.h>

#define N_NODES 25000
#define N_EDGES 400000
#define NFEAT   256
#define NHID    32
#define NHEAD   12
#define HC      384
#define NEG_SLOPE 0.2f
#define NBLK    ((N_NODES + 255) / 256)
#define BPAD    40   // LDS row pitch for B-tile (2-way bank aliasing only)

typedef __attribute__((ext_vector_type(8))) short short8;
typedef __attribute__((ext_vector_type(4))) float floatx4;

__device__ __forceinline__ float bf2f(unsigned short u) {
    union { unsigned int i; float f; } v; v.i = ((unsigned int)u) << 16; return v.f;
}
__device__ __forceinline__ unsigned short f2bf(float f) {
    union { float f; unsigned int i; } v; v.f = f;
    unsigned int x = v.i;
    unsigned int r = (x + 0x7FFFu + ((x >> 16) & 1u)) >> 16;
    return (unsigned short)r;
}
__device__ __forceinline__ int clampN(int s) {
    return ((unsigned)s < (unsigned)N_NODES) ? s : 0;
}
__device__ __forceinline__ float ldf(const void* p, size_t i, int isF32) {
    return isF32 ? ((const float*)p)[i] : bf2f(((const unsigned short*)p)[i]);
}
__device__ __forceinline__ int ldi(const void* p, size_t i, int isI64) {
    return isI64 ? (int)((const unsigned int*)p)[2 * i] : ((const int*)p)[i];
}

// ---------------- dtype detection (1 block) ----------------
__global__ void detect_kernel(const unsigned short* __restrict__ xr,
                              const unsigned int* __restrict__ eir,
                              int* __restrict__ flags) {
    __shared__ int sF, sI;
    if (threadIdx.x == 0) { sF = 0; sI = 0; }
    __syncthreads();
    int t = threadIdx.x;
    int cf = 0, ci = 0;
#pragma unroll
    for (int i = 0; i < 4; i++) {
        unsigned short u = xr[2 * (t * 4 + i)];
        int e = (u >> 7) & 0xFF;
        if (e >= 100 && e <= 140) cf++;
        unsigned int v = eir[2 * (t * 4 + i) + 1];
        if (v == 0u) ci++;
    }
    atomicAdd(&sF, cf);
    atomicAdd(&sI, ci);
    __syncthreads();
    if (threadIdx.x == 0) {
        flags[0] = (sF >= 614) ? 0 : 1;   // 1 -> float inputs are f32
        flags[1] = (sI >= 512) ? 1 : 0;   // 1 -> edge_index is i64
    }
}

// ---------------- prep: M1 fold + W1/W2 transpose to bf16 ----------------
__global__ void prep_kernel(const void* __restrict__ We1,
                            const void* __restrict__ att_e,
                            const void* __restrict__ W1,
                            const void* __restrict__ W2,
                            const int* __restrict__ flags,
                            float* __restrict__ M1,
                            unsigned short* __restrict__ Wt1,
                            unsigned short* __restrict__ Wt2) {
    int isF32 = flags[0];
    int id = blockIdx.x * 256 + threadIdx.x;
    if (id < 384) {
        int k = id / 12, h = id % 12;
        float s = 0.f;
        for (int c = 0; c < 32; c++)
            s += ldf(We1, (size_t)k * HC + h * 32 + c, isF32) *
                 ldf(att_e, (size_t)h * 32 + c, isF32);
        M1[k * 12 + h] = s;
        return;
    }
    int id1 = id - 384;
    if (id1 < 384 * 256) {
        int n = id1 / 256, k = id1 % 256;
        Wt1[(size_t)n * 256 + k] = f2bf(ldf(W1, (size_t)k * HC + n, isF32));
        return;
    }
    int id2 = id1 - 384 * 256;
    if (id2 < 384 * 384) {
        int n = id2 / 384, k = id2 % 384;
        Wt2[(size_t)n * 384 + k] = f2bf(ldf(W2, (size_t)k * HC + n, isF32));
    }
}

// ---------------- CSR build ----------------
__global__ void hist_kernel(const void* __restrict__ ei, const int* __restrict__ flags,
                            int* __restrict__ cnt) {
    int isI64 = flags[1];
    int e = blockIdx.x * 256 + threadIdx.x;
    if (e < N_EDGES) {
        int d = clampN(ldi(ei, (size_t)N_EDGES + e, isI64));
        atomicAdd(&cnt[d], 1);
    }
}

// 3-phase device-wide scan
__global__ void blockscan_kernel(const int* __restrict__ cnt, int* __restrict__ incl,
                                 int* __restrict__ bsum) {
    __shared__ int buf[256];
    int i = blockIdx.x * 256 + threadIdx.x;
    int v = (i < N_NODES) ? cnt[i] : 0;
    buf[threadIdx.x] = v;
    __syncthreads();
    for (int off = 1; off < 256; off <<= 1) {
        int t = (threadIdx.x >= off) ? buf[threadIdx.x - off] : 0;
        __syncthreads();
        buf[threadIdx.x] += t;
        __syncthreads();
    }
    if (i < N_NODES) incl[i] = buf[threadIdx.x];
    if (threadIdx.x == 255) bsum[blockIdx.x] = buf[255];
}

__global__ void bscan_kernel(const int* __restrict__ bsum, int* __restrict__ boff) {
    __shared__ int buf[128];
    int t = threadIdx.x;
    int v = (t < NBLK) ? bsum[t] : 0;
    buf[t] = v;
    __syncthreads();
    for (int off = 1; off < 128; off <<= 1) {
        int u = (t >= off) ? buf[t - off] : 0;
        __syncthreads();
        buf[t] += u;
        __syncthreads();
    }
    if (t < NBLK) boff[t] = buf[t] - v;
}

__global__ void finalize_kernel(const int* __restrict__ incl, const int* __restrict__ boff,
                                const int* __restrict__ cnt,
                                int* __restrict__ rowptr, int* __restrict__ wofs) {
    int i = blockIdx.x * 256 + threadIdx.x;
    if (i == 0) rowptr[0] = 0;
    if (i < N_NODES) {
        int v = incl[i] + boff[blockIdx.x];
        rowptr[i + 1] = v;
        wofs[i] = v - cnt[i];
    }
}

// minimal scatter: 8 bytes per edge (src, edge_id)
__global__ void scatter_kernel(const void* __restrict__ ei, const int* __restrict__ flags,
                               int* __restrict__ wofs, int2* __restrict__ pairs) {
    int isI64 = flags[1];
    int e = blockIdx.x * 256 + threadIdx.x;
    if (e >= N_EDGES) return;
    int d = clampN(ldi(ei, (size_t)N_EDGES + e, isI64));
    int pos = atomicAdd(&wofs[d], 1);
    if ((unsigned)pos >= (unsigned)N_EDGES) return;
    pairs[pos] = make_int2(clampN(ldi(ei, (size_t)e, isI64)), e);
}

// folded edge attention in coalesced edge order
__global__ void ae_kernel(const void* __restrict__ ea, const int* __restrict__ flags,
                          const float* __restrict__ M1,
                          unsigned short* __restrict__ ae_edge) {
    __shared__ float sM[384];
    for (int i = threadIdx.x; i < 384; i += 256) sM[i] = M1[i];
    __syncthreads();
    int isF32 = flags[0];
    int e = blockIdx.x * 256 + threadIdx.x;
    if (e >= N_EDGES) return;
    float a[32];
    if (isF32) {
        const float4* r4 = (const float4*)((const float*)ea + (size_t)e * 32);
#pragma unroll
        for (int i = 0; i < 8; i++) {
            float4 v = r4[i];
            a[4 * i] = v.x; a[4 * i + 1] = v.y; a[4 * i + 2] = v.z; a[4 * i + 3] = v.w;
        }
    } else {
        const unsigned short* r = (const unsigned short*)ea + (size_t)e * 32;
#pragma unroll
        for (int i = 0; i < 32; i++) a[i] = bf2f(r[i]);
    }
    float ev[12];
#pragma unroll
    for (int h = 0; h < 12; h++) ev[h] = 0.f;
#pragma unroll
    for (int k = 0; k < 32; k++)
#pragma unroll
        for (int h = 0; h < 12; h++) ev[h] += a[k] * sM[k * 12 + h];
    unsigned int w[6];
#pragma unroll
    for (int i = 0; i < 6; i++)
        w[i] = (unsigned int)f2bf(ev[2 * i]) | ((unsigned int)f2bf(ev[2 * i + 1]) << 16);
    uint2* dst = (uint2*)(ae_edge + (size_t)e * 12);
    dst[0] = make_uint2(w[0], w[1]);
    dst[1] = make_uint2(w[2], w[3]);
    dst[2] = make_uint2(w[4], w[5]);
}

// ---------------- full-N MFMA GEMM: wave = 16 rows x 384 cols; A read ONCE ----------------
// B-tile (384 cols x 32 k) staged in LDS per K-step, BPAD=40 pitch (2-way banks = free).
__global__ __launch_bounds__(256) void gemm_mfma(const void* __restrict__ A,
                                                 const unsigned short* __restrict__ Bt,
                                                 const int* __restrict__ flags,
                                                 int aFromFlag,
                                                 unsigned short* __restrict__ C,
                                                 int M, int K) {
    __shared__ unsigned short sB[384 * BPAD];   // 30720 B
    int aF32 = aFromFlag ? flags[0] : 0;
    int lane = threadIdx.x & 63;
    int w = threadIdx.x >> 6;
    int m0 = blockIdx.x * 64 + w * 16;
    int r = lane & 15, q = lane >> 4;
    int row = m0 + r;
    if (row >= M) row = M - 1;
    floatx4 acc[24];
#pragma unroll
    for (int j = 0; j < 24; j++) acc[j] = (floatx4){0.f, 0.f, 0.f, 0.f};
    for (int k0 = 0; k0 < K; k0 += 32) {
        // stage B-tile: 384 cols x 32 k = 1536 16B-chunks / 256 threads = 6 each
        for (int i = threadIdx.x; i < 384 * 4; i += 256) {
            int col = i >> 2, seg = i & 3;
            *(uint4*)(sB + (size_t)col * BPAD + seg * 8) =
                *(const uint4*)(Bt + (size_t)col * K + k0 + seg * 8);
        }
        __syncthreads();
        short8 a;
        if (aF32) {
            const float4* ap = (const float4*)((const float*)A + (size_t)row * K + k0 + q * 8);
            float4 u = ap[0], v = ap[1];
            a[0] = (short)f2bf(u.x); a[1] = (short)f2bf(u.y);
            a[2] = (short)f2bf(u.z); a[3] = (short)f2bf(u.w);
            a[4] = (short)f2bf(v.x); a[5] = (short)f2bf(v.y);
            a[6] = (short)f2bf(v.z); a[7] = (short)f2bf(v.w);
        } else {
            a = *(const short8*)((const unsigned short*)A + (size_t)row * K + k0 + q * 8);
        }
#pragma unroll
        for (int j = 0; j < 24; j++) {
            int col = 16 * j + r;
            short8 b = *(const short8*)(sB + (size_t)col * BPAD + q * 8);
            acc[j] = __builtin_amdgcn_mfma_f32_16x16x32_bf16(a, b, acc[j], 0, 0, 0);
        }
        __syncthreads();
    }
#pragma unroll
    for (int j = 0; j < 24; j++) {
        int col = 16 * j + r;
#pragma unroll
        for (int t = 0; t < 4; t++) {
            int orow = m0 + q * 4 + t;
            if (orow < M) C[(size_t)orow * HC + col] = f2bf(acc[j][t]);
        }
    }
}

// ---------------- per-(node,head) attention logits ----------------
__global__ void att_kernel(const unsigned short* __restrict__ hx,
                           const void* __restrict__ att_src,
                           const void* __restrict__ att_dst,
                           const int* __restrict__ flags,
                           float* __restrict__ a_s, float* __restrict__ a_d) {
    int isF32 = flags[0];
    int id = blockIdx.x * 256 + threadIdx.x;
    if (id >= N_NODES * NHEAD) return;
    int n = id / 12, h = id % 12;
    const unsigned short* row = hx + (size_t)n * HC + h * 32;
    float s = 0.f, d = 0.f;
#pragma unroll
    for (int c = 0; c < 32; c++) {
        float v = bf2f(row[c]);
        s += v * ldf(att_src, (size_t)h * 32 + c, isF32);
        d += v * ldf(att_dst, (size_t)h * 32 + c, isF32);
    }
    a_s[id] = s;
    a_d[id] = d;
}

// ---------------- segment softmax: stores UNNORMALIZED exp + per-node rden ----------------
__global__ __launch_bounds__(256) void softmax_kernel(const float* __restrict__ a_s,
                                                      const float* __restrict__ a_d,
                                                      const int* __restrict__ rowptr,
                                                      const int2* __restrict__ pairs,
                                                      const unsigned short* __restrict__ ae_edge,
                                                      unsigned short* __restrict__ alpha_e,
                                                      float* __restrict__ exl_out,
                                                      float* __restrict__ rden_out,
                                                      int has_ae) {
    int lane = threadIdx.x & 63;
    int node = blockIdx.x * 4 + (threadIdx.x >> 6);
    if (node >= N_NODES) return;
    int start = rowptr[node], end = rowptr[node + 1];
    if (start < 0) start = 0;
    if (end > N_EDGES) end = N_EDGES;
    int deg = end - start;
    float adn[12], asn[12], mx[12], sae[12];
#pragma unroll
    for (int h = 0; h < 12; h++) {
        adn[h] = a_d[node * 12 + h];
        asn[h] = a_s[node * 12 + h];
        mx[h] = -1e30f;
        sae[h] = 0.f;
    }
    float invdeg = 1.f / fmaxf((float)deg, 1.f);

    if (deg <= 64) {
        int p = start + lane;
        bool act = p < end;
        int2 pe = act ? pairs[p] : make_int2(0, 0);
        int s = clampN(pe.x);
        int eid = ((unsigned)pe.y < (unsigned)N_EDGES) ? pe.y : 0;
        float ev[12];
        float aev[12];
        if (has_ae && act) {
            const uint2* src = (const uint2*)(ae_edge + (size_t)eid * 12);
            uint2 w0 = src[0], w1 = src[1], w2 = src[2];
            unsigned int ws[6] = {w0.x, w0.y, w1.x, w1.y, w2.x, w2.y};
#pragma unroll
            for (int i = 0; i < 6; i++) {
                aev[2 * i]     = bf2f((unsigned short)(ws[i] & 0xFFFF));
                aev[2 * i + 1] = bf2f((unsigned short)(ws[i] >> 16));
            }
        } else {
#pragma unroll
            for (int h = 0; h < 12; h++) aev[h] = 0.f;
        }
        if (act) {
            const float4* as4 = (const float4*)(a_s + (size_t)s * 12);
            float4 f0 = as4[0], f1 = as4[1], f2 = as4[2];
            float asv[12] = {f0.x, f0.y, f0.z, f0.w, f1.x, f1.y, f1.z, f1.w,
                             f2.x, f2.y, f2.z, f2.w};
#pragma unroll
            for (int h = 0; h < 12; h++) {
                float v = asv[h] + adn[h] + aev[h];
                sae[h] = aev[h];
                v = v > 0.f ? v : NEG_SLOPE * v;
                ev[h] = v;
                mx[h] = v;
            }
        } else {
#pragma unroll
            for (int h = 0; h < 12; h++) ev[h] = -1e30f;
        }
#pragma unroll
        for (int off = 1; off < 64; off <<= 1) {
#pragma unroll
            for (int h = 0; h < 12; h++) {
                mx[h] = fmaxf(mx[h], __shfl_xor(mx[h], off));
                if (has_ae) sae[h] += __shfl_xor(sae[h], off);
            }
        }
        float el[12], den[12], ex[12];
#pragma unroll
        for (int h = 0; h < 12; h++) {
            float v = asn[h] + adn[h] + (has_ae ? sae[h] * invdeg : 0.f);
            v = v > 0.f ? v : NEG_SLOPE * v;
            el[h] = v;
            mx[h] = fmaxf(mx[h], v);
            ex[h] = act ? expf(ev[h] - mx[h]) : 0.f;
            den[h] = ex[h];
        }
#pragma unroll
        for (int off = 1; off < 64; off <<= 1) {
#pragma unroll
            for (int h = 0; h < 12; h++) den[h] += __shfl_xor(den[h], off);
        }
        if (act) {
            unsigned int w[6];
#pragma unroll
            for (int i = 0; i < 6; i++)
                w[i] = (unsigned int)f2bf(ex[2 * i]) | ((unsigned int)f2bf(ex[2 * i + 1]) << 16);
            uint2* dst = (uint2*)(alpha_e + (size_t)p * 12);
            dst[0] = make_uint2(w[0], w[1]);
            dst[1] = make_uint2(w[2], w[3]);
            dst[2] = make_uint2(w[4], w[5]);
        }
        if (lane == 0) {
#pragma unroll
            for (int h = 0; h < 12; h++) {
                float exl = expf(el[h] - mx[h]);
                exl_out[node * 12 + h] = exl;
                rden_out[node * 12 + h] = 1.f / (den[h] + exl);
            }
        }
    } else {
        for (int p = start + lane; p < end; p += 64) {
            int2 pe = pairs[p];
            int s = clampN(pe.x);
            int eid = ((unsigned)pe.y < (unsigned)N_EDGES) ? pe.y : 0;
#pragma unroll
            for (int h = 0; h < 12; h++) {
                float v = a_s[(size_t)s * 12 + h] + adn[h];
                if (has_ae) {
                    float a = bf2f(ae_edge[(size_t)eid * 12 + h]);
                    sae[h] += a;
                    v += a;
                }
                v = v > 0.f ? v : NEG_SLOPE * v;
                alpha_e[(size_t)p * 12 + h] = f2bf(v);
                mx[h] = fmaxf(mx[h], v);
            }
        }
#pragma unroll
        for (int off = 1; off < 64; off <<= 1) {
#pragma unroll
            for (int h = 0; h < 12; h++) {
                mx[h] = fmaxf(mx[h], __shfl_xor(mx[h], off));
                if (has_ae) sae[h] += __shfl_xor(sae[h], off);
            }
        }
        float el[12], den[12];
#pragma unroll
        for (int h = 0; h < 12; h++) {
            float v = asn[h] + adn[h] + (has_ae ? sae[h] * invdeg : 0.f);
            v = v > 0.f ? v : NEG_SLOPE * v;
            el[h] = v;
            mx[h] = fmaxf(mx[h], v);
            den[h] = 0.f;
        }
        for (int p = start + lane; p < end; p += 64) {
#pragma unroll
            for (int h = 0; h < 12; h++) {
                float ex = expf(bf2f(alpha_e[(size_t)p * 12 + h]) - mx[h]);
                alpha_e[(size_t)p * 12 + h] = f2bf(ex);
                den[h] += ex;
            }
        }
#pragma unroll
        for (int off = 1; off < 64; off <<= 1) {
#pragma unroll
            for (int h = 0; h < 12; h++) den[h] += __shfl_xor(den[h], off);
        }
        if (lane == 0) {
#pragma unroll
            for (int h = 0; h < 12; h++) {
                float exl = expf(el[h] - mx[h]);
                exl_out[node * 12 + h] = exl;
                rden_out[node * 12 + h] = 1.f / (den[h] + exl);
            }
        }
    }
}

// ---------------- layer-1 aggregation (rden applied here) + bias + ELU -> h1 ----------------
__global__ __launch_bounds__(256) void agg1_kernel(const unsigned short* __restrict__ hx,
                                                   const unsigned short* __restrict__ alpha_e,
                                                   const float* __restrict__ exl,
                                                   const float* __restrict__ rden,
                                                   const int* __restrict__ rowptr,
                                                   const int2* __restrict__ pairs,
                                                   const void* __restrict__ b1,
                                                   const int* __restrict__ flags,
                                                   unsigned short* __restrict__ h1) {
    int isF32 = flags[0];
    int lane = threadIdx.x & 63;
    int node = blockIdx.x * 4 + (threadIdx.x >> 6);
    if (node >= N_NODES) return;
    int start = rowptr[node], end = rowptr[node + 1];
    if (start < 0) start = 0;
    if (end > N_EDGES) end = N_EDGES;
    float acc[6];
    const unsigned short* hxn = hx + (size_t)node * HC;
#pragma unroll
    for (int j = 0; j < 6; j++) {
        int ch = lane + 64 * j;
        acc[j] = exl[node * 12 + (ch >> 5)] * bf2f(hxn[ch]);
    }
    for (int p = start; p < end; p++) {
        int s = clampN(pairs[p].x);
        const unsigned short* hxs = hx + (size_t)s * HC;
#pragma unroll
        for (int j = 0; j < 6; j++) {
            int ch = lane + 64 * j;
            acc[j] += bf2f(alpha_e[(size_t)p * 12 + (ch >> 5)]) * bf2f(hxs[ch]);
        }
    }
#pragma unroll
    for (int j = 0; j < 6; j++) {
        int ch = lane + 64 * j;
        float v = acc[j] * rden[node * 12 + (ch >> 5)] + ldf(b1, (size_t)ch, isF32);
        v = v > 0.f ? v : expm1f(v);
        h1[(size_t)node * HC + ch] = f2bf(v);
    }
}

// ---------------- layer-2 aggregation + head-mean + bias + log_softmax (f32 out) ----------------
__global__ __launch_bounds__(256) void agg2_kernel(const unsigned short* __restrict__ hx,
                                                   const unsigned short* __restrict__ alpha_e,
                                                   const float* __restrict__ exl,
                                                   const float* __restrict__ rden,
                                                   const int* __restrict__ rowptr,
                                                   const int2* __restrict__ pairs,
                                                   const void* __restrict__ b2,
                                                   const int* __restrict__ flags,
                                                   float* __restrict__ out) {
    int isF32 = flags[0];
    int lane = threadIdx.x & 63;
    int node = blockIdx.x * 4 + (threadIdx.x >> 6);
    if (node >= N_NODES) return;
    int start = rowptr[node], end = rowptr[node + 1];
    if (start < 0) start = 0;
    if (end > N_EDGES) end = N_EDGES;
    float acc[6];
    const unsigned short* hxn = hx + (size_t)node * HC;
#pragma unroll
    for (int j = 0; j < 6; j++) {
        int ch = lane + 64 * j;
        acc[j] = exl[node * 12 + (ch >> 5)] * bf2f(hxn[ch]);
    }
    for (int p = start; p < end; p++) {
        int s = clampN(pairs[p].x);
        const unsigned short* hxs = hx + (size_t)s * HC;
#pragma unroll
        for (int j = 0; j < 6; j++) {
            int ch = lane + 64 * j;
            acc[j] += bf2f(alpha_e[(size_t)p * 12 + (ch >> 5)]) * bf2f(hxs[ch]);
        }
    }
    float local = 0.f;
#pragma unroll
    for (int j = 0; j < 6; j++) {
        int ch = lane + 64 * j;
        local += acc[j] * rden[node * 12 + (ch >> 5)];
    }
    local += __shfl_xor(local, 32);
    int c = lane & 31;
    float h2v = local * (1.f / 12.f) + ldf(b2, (size_t)c, isF32);
    float m = h2v;
#pragma unroll
    for (int off = 1; off < 32; off <<= 1) m = fmaxf(m, __shfl_xor(m, off));
    float s = expf(h2v - m);
#pragma unroll
    for (int off = 1; off < 32; off <<= 1) s += __shfl_xor(s, off);
    float lsm = h2v - m - logf(s);
    if (lane < 32) {
        out[(size_t)node * 32 + c] = h2v;
        out[(size_t)N_NODES * 32 + (size_t)node * 32 + c] = lsm;
    }
}

extern "C" void kernel_launch(void* const* d_in, const int* in_sizes, int n_in,
                              void* d_out, int out_size, void* d_ws, size_t ws_size,
                              hipStream_t stream) {
    const void* x        = d_in[0];
    const void* ei       = d_in[1];
    const void* ea       = d_in[2];
    const void* W1       = d_in[3];
    const void* att_src1 = d_in[4];
    const void* att_dst1 = d_in[5];
    const void* We1      = d_in[6];
    const void* att_e1   = d_in[7];
    const void* b1       = d_in[8];
    const void* W2       = d_in[9];
    const void* att_src2 = d_in[10];
    const void* att_dst2 = d_in[11];
    const void* b2       = d_in[12];
    float* out = (float*)d_out;

    char* ws = (char*)d_ws;
    size_t off = 0;
    auto alloc = [&](size_t bytes) -> void* {
        void* p = ws + off;
        off = (off + bytes + 255) & ~(size_t)255;
        return p;
    };
    int*            flags   = (int*)alloc(16);
    float*          M1      = (float*)alloc((size_t)384 * 4);
    int*            rowptr  = (int*)alloc((size_t)(N_NODES + 1) * 4);
    int*            cnt     = (int*)alloc((size_t)N_NODES * 4);
    int*            wofs    = (int*)alloc((size_t)N_NODES * 4);
    int*            incl    = (int*)alloc((size_t)N_NODES * 4);
    int*            bsum    = (int*)alloc((size_t)NBLK * 4);
    int*            boff    = (int*)alloc((size_t)NBLK * 4);
    float*          a_s     = (float*)alloc((size_t)N_NODES * 12 * 4);
    float*          a_d     = (float*)alloc((size_t)N_NODES * 12 * 4);
    float*          exl     = (float*)alloc((size_t)N_NODES * 12 * 4);
    float*          rden    = (float*)alloc((size_t)N_NODES * 12 * 4);
    int2*           pairs   = (int2*)alloc((size_t)N_EDGES * 8);
    unsigned short* alpha_e = (unsigned short*)alloc((size_t)N_EDGES * 12 * 2);
    unsigned short* hx      = (unsigned short*)alloc((size_t)N_NODES * HC * 2);
    // h1 aliases ae_edge: ae_edge dead after softmax1, h1 born in agg1 (after).
    unsigned short* h1      = (unsigned short*)alloc((size_t)N_NODES * HC * 2);
    unsigned short* ae_edge = h1;
    unsigned short* Wt1     = (unsigned short*)alloc((size_t)384 * 256 * 2);
    unsigned short* Wt2     = (unsigned short*)alloc((size_t)384 * 384 * 2);

    hipMemsetAsync(cnt, 0, (size_t)N_NODES * 4, stream);
    detect_kernel<<<1, 256, 0, stream>>>((const unsigned short*)x, (const unsigned int*)ei, flags);
    prep_kernel<<<(384 + 384 * 256 + 384 * 384 + 255) / 256, 256, 0, stream>>>(
        We1, att_e1, W1, W2, flags, M1, Wt1, Wt2);
    hist_kernel<<<(N_EDGES + 255) / 256, 256, 0, stream>>>(ei, flags, cnt);
    blockscan_kernel<<<NBLK, 256, 0, stream>>>(cnt, incl, bsum);
    bscan_kernel<<<1, 128, 0, stream>>>(bsum, boff);
    finalize_kernel<<<NBLK, 256, 0, stream>>>(incl, boff, cnt, rowptr, wofs);
    scatter_kernel<<<(N_EDGES + 255) / 256, 256, 0, stream>>>(ei, flags, wofs, pairs);
    ae_kernel<<<(N_EDGES + 255) / 256, 256, 0, stream>>>(ea, flags, M1, ae_edge);
    // layer 1
    gemm_mfma<<<(N_NODES + 63) / 64, 256, 0, stream>>>(x, Wt1, flags, 1, hx, N_NODES, NFEAT);
    att_kernel<<<(N_NODES * 12 + 255) / 256, 256, 0, stream>>>(hx, att_src1, att_dst1, flags,
                                                               a_s, a_d);
    softmax_kernel<<<(N_NODES + 3) / 4, 256, 0, stream>>>(a_s, a_d, rowptr, pairs, ae_edge,
                                                          alpha_e, exl, rden, 1);
    agg1_kernel<<<(N_NODES + 3) / 4, 256, 0, stream>>>(hx, alpha_e, exl, rden, rowptr, pairs,
                                                       b1, flags, h1);
    // layer 2
    gemm_mfma<<<(N_NODES + 63) / 64, 256, 0, stream>>>(h1, Wt2, flags, 0, hx, N_NODES, HC);
    att_kernel<<<(N_NODES * 12 + 255) / 256, 256, 0, stream>>>(hx, att_src2, att_dst2, flags,
                                                               a_s, a_d);
    softmax_kernel<<<(N_NODES + 3) / 4, 256, 0, stream>>>(a_s, a_d, rowptr, pairs, ae_edge,
                                                          alpha_e, exl, rden, 0);
    agg2_kernel<<<(N_NODES + 3) / 4, 256, 0, stream>>>(hx, alpha_e, exl, rden, rowptr, pairs,
                                                       b2, flags, out);
}